// Round 6
// baseline (15371.814 us; speedup 1.0000x reference)
//
#include <hip/hip_runtime.h>
#include <cstddef>
#include <cstdint>

#define T_TOTAL 32768
#define IN_SZ   128
#define HID     256
#define G4      1024
#define TA      48
#define TD      12
#define NDEC    4
#define N_WINS  (T_TOTAL - IN_SZ + 1)   // 32641
#define N_OUT   (N_WINS - TA)           // 32593
#define MPAD    32640                   // padded row count (255*128)
#define W48     48
#define P8      8
#define NSTEPS  (W48 + P8)              // 56

// ---------------- workspace layout (float offsets) ----------------
#define LEVS_OFF   ((size_t)0)                                    // 32768
#define PBW_OFF(l) ((size_t)32768 + (size_t)(l)*131072)           // Whh bf16 frags, 4 x 131072
#define PBI0_OFF   ((size_t)557056)                               // Wih0 frags, 65536
#define PBI_OFF(l) ((size_t)622592 + (size_t)((l)-1)*131072)      // Wih1..3 frags
#define PBNL_OFF   ((size_t)1015808)                              // nlW frags, 32768
#define BS_OFF(l)  ((size_t)1048576 + (size_t)(l)*1024)           // 4 x 1024
#define XPB_OFF    ((size_t)1052672)                              // XP bf16 [32640][1024] = 16711680 fl
#define HB_OFF(l)  ((size_t)17764352 + (size_t)(l)*4177920)       // h bf16 [32640][256], 4 x
#define OUTF_OFF   ((size_t)34476032)                             // fp32 [32640][256] = 8355840
#define WS_FLOATS  ((size_t)(34476032 + 8355840))                 // 42831872 (~171 MB)

typedef short s16x8 __attribute__((ext_vector_type(8)));
typedef float f32x16 __attribute__((ext_vector_type(16)));
typedef unsigned short ushort_t;
typedef unsigned int uint_t;

typedef const __attribute__((address_space(1))) unsigned int* as1_u32p;
typedef __attribute__((address_space(3))) unsigned int* as3_u32p;
__device__ __forceinline__ void gload_lds16(const void* g, void* lds) {
  __builtin_amdgcn_global_load_lds((as1_u32p)g, (as3_u32p)lds, 16, 0, 0);
}

__device__ __forceinline__ float sig_fast(float x) {
  return __builtin_amdgcn_rcpf(1.f + __expf(-x));
}
__device__ __forceinline__ float tanh_fast(float x) {
  float ax = fabsf(x);
  float e  = __expf(-2.f * ax);
  float r  = (1.f - e) * __builtin_amdgcn_rcpf(1.f + e);
  return copysignf(r, x);
}
__device__ __forceinline__ ushort_t f2bf(float f) {
  uint_t u = __builtin_bit_cast(uint_t, f);
  uint_t r = (u + 0x7fffu + ((u >> 16) & 1u)) >> 16;
  return (ushort_t)r;
}
__device__ __forceinline__ float bf2f(uint_t us) {
  return __builtin_bit_cast(float, us << 16);
}

// ---------------- levels (contraction, 64-step lookback) ----------------
__global__ void levels_kernel(const float* __restrict__ train,
                              const int* __restrict__ idxs,
                              const float* __restrict__ a0,
                              const float* __restrict__ tau_p,
                              float* __restrict__ levs) {
  int t = blockIdx.x * blockDim.x + threadIdx.x;
  if (t >= T_TOTAL) return;
  int ix   = idxs[0];
  float a  = 1.f / (1.f + __expf(-a0[ix]));
  float fl = tau_p[ix] * 1.0f;
  int q0 = (t >= 64) ? (t - 64) : 0;
  float p = fmaxf(train[q0], fl);
  for (int s = q0 + 1; s <= t; ++s)
    p = fmaxf(a * train[s] + (1.f - a) * p, fl);
  levs[t] = p;
}

// ---------------- act output (exact) ----------------
__global__ void act_kernel(const float* __restrict__ train,
                           const float* __restrict__ levs,
                           float* __restrict__ outp) {
  int idx = blockIdx.x * blockDim.x + threadIdx.x;
  if (idx >= N_OUT * NDEC) return;
  int w = idx >> 2, dec = idx & 3;
  int base = w + IN_SZ + dec * TD;
  float m = train[base];
#pragma unroll
  for (int j = 1; j < TD; ++j) m = fmaxf(m, train[base + j]);
  outp[idx] = m / levs[w + IN_SZ - 1];
}

// ---------------- packing ----------------
// B-frag stream for mfma_f32_32x32x16_bf16 over cols in gate-major packed order:
// global packed col N = wv*256 + g*64 + cp ; frag = wv*(K16*8) + s16*8 + t
// element [l][j]: k = s16*16 + (l>>5)*8 + j ; col-in-block = t*32+(l&31) -> g=t>>1, cp=(t&1)*32+(l&31)
__global__ void pack_pb_kernel(const float* __restrict__ Wsrc, ushort_t* __restrict__ PB, int K16) {
  int idx = blockIdx.x * blockDim.x + threadIdx.x;
  if (idx >= K16 * 16384) return;
  int j = idx & 7;
  int l = (idx >> 3) & 63;
  int frag = idx >> 9;
  int t = frag & 7;
  int s16 = (frag >> 3) % K16;
  int wv  = (frag >> 3) / K16;
  int K = K16 * 16;
  int k = s16 * 16 + ((l >> 5) << 3) + j;
  int g = t >> 1;
  int cp = ((t & 1) << 5) + (l & 31);
  int orow = g * HID + wv * 64 + cp;
  PB[idx] = f2bf(Wsrc[(size_t)orow * K + k]);
}
// nlW frags: natural cols, N=256 as 2 blocks of 128 (4 tiles each)
__global__ void pack_nl_kernel(const float* __restrict__ nlW, ushort_t* __restrict__ PBnl) {
  int idx = blockIdx.x * blockDim.x + threadIdx.x;
  if (idx >= 65536) return;
  int j = idx & 7;
  int l = (idx >> 3) & 63;
  int frag = idx >> 9;
  int t = frag & 3;
  int s16 = (frag >> 2) & 15;
  int nb = frag >> 6;
  int n = nb * 128 + t * 32 + (l & 31);
  int k = s16 * 16 + ((l >> 5) << 3) + j;
  PBnl[idx] = f2bf(nlW[(size_t)n * HID + k]);
}
__global__ void pack_b_kernel(const float* __restrict__ bih, const float* __restrict__ bhh,
                              float* __restrict__ bs) {
  int idx = blockIdx.x * blockDim.x + threadIdx.x;
  if (idx >= G4) return;
  int g = (idx >> 6) & 3;
  int c = ((idx >> 8) << 6) + (idx & 63);
  bs[idx] = bih[g * HID + c] + bhh[g * HID + c];
}

// ---------------- MFMA input-projection GEMM (layers 1-3) ----------------
__global__ __launch_bounds__(256, 1) void gemm_xp_kernel(
    const ushort_t* __restrict__ Ab,   // [MPAD][256] bf16 (h of prev layer)
    const ushort_t* __restrict__ PBih, // frag stream (K16=16)
    const float* __restrict__ Bsum,    // [1024] gate-major packed
    ushort_t* __restrict__ XPb) {      // [MPAD][1024]
  int tid = threadIdx.x;
  int w = tid >> 6, l = tid & 63, hi = l >> 5, lm = l & 31;
  int mb = blockIdx.x, nb = blockIdx.y;
  int m = mb * 128 + w * 32 + lm;
  const s16x8* pbw = ((const s16x8*)PBih) + (size_t)nb * 8192;
  const s16x8* arow = (const s16x8*)(Ab + (size_t)m * 256);
  f32x16 acc[8];
#pragma unroll
  for (int t = 0; t < 8; ++t)
#pragma unroll
    for (int e = 0; e < 16; ++e) acc[t][e] = 0.f;
#pragma unroll
  for (int s16 = 0; s16 < 16; ++s16) {
    s16x8 af = arow[s16 * 2 + hi];
#pragma unroll
    for (int t = 0; t < 8; ++t) {
      s16x8 bf = pbw[(size_t)(s16 * 8 + t) * 64 + l];
      acc[t] = __builtin_amdgcn_mfma_f32_32x32x16_bf16(af, bf, acc[t], 0, 0, 0);
    }
  }
  float bsv[8];
#pragma unroll
  for (int t = 0; t < 8; ++t) bsv[t] = Bsum[nb * 256 + t * 32 + lm];
#pragma unroll
  for (int rr = 0; rr < 16; ++rr) {
    int r  = (rr & 3) + ((rr >> 2) << 3) + (hi << 2);
    int mo = mb * 128 + w * 32 + r;
    if (mo >= N_OUT) continue;
#pragma unroll
    for (int ch = 0; ch < 2; ++ch) {
      uint_t lo = (uint_t)f2bf(acc[0 + ch][rr] + bsv[0 + ch]) |
                  ((uint_t)f2bf(acc[2 + ch][rr] + bsv[2 + ch]) << 16);
      uint_t hi2 = (uint_t)f2bf(acc[4 + ch][rr] + bsv[4 + ch]) |
                   ((uint_t)f2bf(acc[6 + ch][rr] + bsv[6 + ch]) << 16);
      uint64_t v = (uint64_t)lo | ((uint64_t)hi2 << 32);
      __builtin_nontemporal_store(v,
          (uint64_t*)(XPb + (size_t)mo * 1024 + nb * 256 + (ch * 32 + lm) * 4));
    }
  }
}

// ---------------- layer-0 window projection (A built from train/lev) -------
__global__ __launch_bounds__(256, 1) void gemm_win_kernel(
    const float* __restrict__ train, const float* __restrict__ levs,
    const ushort_t* __restrict__ PBih0, // frag stream (K16=8)
    const float* __restrict__ Bsum,
    ushort_t* __restrict__ XPb) {
  int tid = threadIdx.x;
  int w = tid >> 6, l = tid & 63, hi = l >> 5, lm = l & 31;
  int mb = blockIdx.x, nb = blockIdx.y;
  int m = mb * 128 + w * 32 + lm;                 // <= 32639; train reads <= 32766
  float s = 1.f / levs[m + IN_SZ - 1];
  const s16x8* pbw = ((const s16x8*)PBih0) + (size_t)nb * 4096;
  f32x16 acc[8];
#pragma unroll
  for (int t = 0; t < 8; ++t)
#pragma unroll
    for (int e = 0; e < 16; ++e) acc[t][e] = 0.f;
#pragma unroll
  for (int s16 = 0; s16 < 8; ++s16) {
    const float* tp = train + m + s16 * 16 + hi * 8;
    s16x8 af;
#pragma unroll
    for (int j = 0; j < 8; ++j) af[j] = (short)f2bf(tp[j] * s);
#pragma unroll
    for (int t = 0; t < 8; ++t) {
      s16x8 bf = pbw[(size_t)(s16 * 8 + t) * 64 + l];
      acc[t] = __builtin_amdgcn_mfma_f32_32x32x16_bf16(af, bf, acc[t], 0, 0, 0);
    }
  }
  float bsv[8];
#pragma unroll
  for (int t = 0; t < 8; ++t) bsv[t] = Bsum[nb * 256 + t * 32 + lm];
#pragma unroll
  for (int rr = 0; rr < 16; ++rr) {
    int r  = (rr & 3) + ((rr >> 2) << 3) + (hi << 2);
    int mo = mb * 128 + w * 32 + r;
    if (mo >= N_OUT) continue;
#pragma unroll
    for (int ch = 0; ch < 2; ++ch) {
      uint_t lo = (uint_t)f2bf(acc[0 + ch][rr] + bsv[0 + ch]) |
                  ((uint_t)f2bf(acc[2 + ch][rr] + bsv[2 + ch]) << 16);
      uint_t hi2 = (uint_t)f2bf(acc[4 + ch][rr] + bsv[4 + ch]) |
                   ((uint_t)f2bf(acc[6 + ch][rr] + bsv[6 + ch]) << 16);
      uint64_t v = (uint64_t)lo | ((uint64_t)hi2 << 32);
      __builtin_nontemporal_store(v,
          (uint64_t*)(XPb + (size_t)mo * 1024 + nb * 256 + (ch * 32 + lm) * 4));
    }
  }
}

// ---------------- MFMA segment-parallel LSTM (v4) ----------------
// M=64 chains/WG, 64 WGs, P=8, W=48. Weights streamed through LDS via
// global_load_lds double-buffer (per-wave-private), counted vmcnt(8) in
// the K-loop (never 0 mid-loop). Per-XCD weight set = 512KB -> L2-resident.
__global__ __launch_bounds__(256, 1) void lstm_mfma_kernel(
    const ushort_t* __restrict__ XPb,  // [MPAD][1024] bf16 gate-packed
    const ushort_t* __restrict__ PBu,  // Whh frag stream
    ushort_t* __restrict__ Hb,         // [MPAD][256] bf16
    int d, int Sper, int L) {
  __shared__ ushort_t Abuf[64][264];      // 33.8 KB
  __shared__ ushort_t Bbuf[4][2][4096];   // 64 KB: per-wave 2 x 8KB chunks
  const int tid = threadIdx.x;
  const int w  = tid >> 6;
  const int l  = tid & 63;
  const int hi = l >> 5;
  const int lm = l & 31;
  const int wu = __builtin_amdgcn_readfirstlane(w);

  for (int idx = tid; idx < 64 * 264; idx += 256) ((ushort_t*)Abuf)[idx] = 0;

  // meta = p0 | (dl << 20) for each of this thread's 32 chains
  int meta[2][16];
#pragma unroll
  for (int mt = 0; mt < 2; ++mt)
#pragma unroll
    for (int rr = 0; rr < 16; ++rr) {
      int r  = mt * 32 + (rr & 3) + ((rr >> 2) << 3) + (hi << 2);
      int id = blockIdx.x * 64 + r;
      int dl = id / Sper;
      int s  = id - dl * Sper;
      int p0 = (dl >= d) ? L : s * P8;     // sentinel never writes (q>=p0 false)
      int ds = (dl >= d) ? 0 : dl;
      meta[mt][rr] = p0 | (ds << 20);
    }
  float cst[2][16][2] = {};

  const char* gsrc = (const char*)PBu + (size_t)wu * 131072 + (size_t)l * 16;
  ushort_t* bb = &Bbuf[wu][0][0];          // per-wave [2][4096]
  __syncthreads();

  // prologue: stage chunk 0 (s16=0) into buf 0
#pragma unroll
  for (int t = 0; t < 8; ++t)
    gload_lds16(gsrc + t * 1024, bb + t * 512);

#pragma unroll 1
  for (int i = 0; i < NSTEPS; ++i) {
    f32x16 acc[2][8];
#pragma unroll
    for (int mt = 0; mt < 2; ++mt)
#pragma unroll
      for (int t = 0; t < 8; ++t)
#pragma unroll
        for (int e = 0; e < 16; ++e) acc[mt][t][e] = 0.f;

#pragma unroll
    for (int s16 = 0; s16 < 16; ++s16) {
      if (s16 < 15) {
        const int nb = (s16 + 1) & 1;
#pragma unroll
        for (int t = 0; t < 8; ++t)
          gload_lds16(gsrc + (size_t)((s16 + 1) * 8 + t) * 1024,
                      bb + nb * 4096 + t * 512);
        asm volatile("s_waitcnt vmcnt(8)" ::: "memory");   // chunk s16 landed
      } else {
        asm volatile("s_waitcnt vmcnt(0)" ::: "memory");   // last chunk
      }
      __builtin_amdgcn_sched_barrier(0);
      s16x8 af0 = *(const s16x8*)&Abuf[lm][s16 * 16 + hi * 8];
      s16x8 af1 = *(const s16x8*)&Abuf[32 + lm][s16 * 16 + hi * 8];
      const ushort_t* bc = bb + (s16 & 1) * 4096;
#pragma unroll
      for (int t = 0; t < 8; ++t) {
        s16x8 bf = *(const s16x8*)(bc + t * 512 + l * 8);
        acc[0][t] = __builtin_amdgcn_mfma_f32_32x32x16_bf16(af0, bf, acc[0][t], 0, 0, 0);
        acc[1][t] = __builtin_amdgcn_mfma_f32_32x32x16_bf16(af1, bf, acc[1][t], 0, 0, 0);
      }
    }
    __syncthreads();   // A-frag reads done before Abuf rewrite

    // prefetch next step's chunk 0 into buf 0 (overlaps gate phase)
    if (i + 1 < NSTEPS) {
#pragma unroll
      for (int t = 0; t < 8; ++t)
        gload_lds16(gsrc + t * 1024, bb + t * 512);
    }

    // ---- gate phase: lane-local i,f,g,o ----
#pragma unroll
    for (int mt = 0; mt < 2; ++mt)
#pragma unroll
      for (int rr = 0; rr < 16; ++rr) {
        int mv = meta[mt][rr];
        int p0 = mv & 0xFFFFF;
        int dl = mv >> 20;
        int q0 = p0 - W48; if (q0 < 0) q0 = 0;
        int q  = q0 + i;
        int p1 = p0 + P8; if (p1 > L) p1 = L;
        int t  = q * d + dl;
        bool valid = (q < p1) && (t < N_OUT);
        int r  = mt * 32 + (rr & 3) + ((rr >> 2) << 3) + (hi << 2);
#pragma unroll
        for (int ch = 0; ch < 2; ++ch) {
          uint64_t xi64 = 0;
          if (valid)
            xi64 = __builtin_nontemporal_load(
                (const uint64_t*)(XPb + (size_t)t * 1024 + w * 256 + (ch * 32 + lm) * 4));
          uint_t xlo = (uint_t)xi64;
          uint_t xhi = (uint_t)(xi64 >> 32);
          float pi = acc[mt][0 + ch][rr] + bf2f(xlo & 0xffffu);
          float pf = acc[mt][2 + ch][rr] + bf2f(xlo >> 16);
          float pg = acc[mt][4 + ch][rr] + bf2f(xhi & 0xffffu);
          float po = acc[mt][6 + ch][rr] + bf2f(xhi >> 16);
          float hh = 0.f;
          if (valid) {
            float cs = sig_fast(pf) * cst[mt][rr][ch] + sig_fast(pi) * tanh_fast(pg);
            cst[mt][rr][ch] = cs;
            hh = sig_fast(po) * tanh_fast(cs);
            if (q >= p0)
              __builtin_nontemporal_store(f2bf(hh),
                  Hb + (size_t)t * HID + w * 64 + ch * 32 + lm);
          }
          Abuf[r][w * 64 + ch * 32 + lm] = f2bf(hh);
        }
      }
    __syncthreads();
  }
}

// ---------------- epilogue: out = tanh((H1+H3) @ nlW^T + nlb), fp32 --------
__global__ __launch_bounds__(256, 2) void gemm_nl_kernel(
    const ushort_t* __restrict__ H1b, const ushort_t* __restrict__ H3b,
    const ushort_t* __restrict__ PBnl, const float* __restrict__ nlb,
    float* __restrict__ OutF) {
  int tid = threadIdx.x;
  int w = tid >> 6, l = tid & 63, hi = l >> 5, lm = l & 31;
  int mb = blockIdx.x, nb = blockIdx.y;
  int m = mb * 128 + w * 32 + lm;
  const s16x8* pbn = ((const s16x8*)PBnl) + (size_t)nb * 4096;
  const s16x8* a1 = (const s16x8*)(H1b + (size_t)m * 256);
  const s16x8* a3 = (const s16x8*)(H3b + (size_t)m * 256);
  f32x16 acc[4];
#pragma unroll
  for (int t = 0; t < 4; ++t)
#pragma unroll
    for (int e = 0; e < 16; ++e) acc[t][e] = 0.f;
#pragma unroll
  for (int s16 = 0; s16 < 16; ++s16) {
    s16x8 af1 = a1[s16 * 2 + hi];
    s16x8 af3 = a3[s16 * 2 + hi];
#pragma unroll
    for (int t = 0; t < 4; ++t) {
      s16x8 bf = pbn[(size_t)(s16 * 4 + t) * 64 + l];
      acc[t] = __builtin_amdgcn_mfma_f32_32x32x16_bf16(af1, bf, acc[t], 0, 0, 0);
      acc[t] = __builtin_amdgcn_mfma_f32_32x32x16_bf16(af3, bf, acc[t], 0, 0, 0);
    }
  }
  float bb[4];
#pragma unroll
  for (int t = 0; t < 4; ++t) bb[t] = nlb[nb * 128 + t * 32 + lm];
#pragma unroll
  for (int rr = 0; rr < 16; ++rr) {
    int r  = (rr & 3) + ((rr >> 2) << 3) + (hi << 2);
    int mo = mb * 128 + w * 32 + r;
    if (mo >= N_OUT) continue;
#pragma unroll
    for (int t = 0; t < 4; ++t)
      OutF[(size_t)mo * 256 + nb * 128 + t * 32 + lm] = tanh_fast(acc[t][rr] + bb[t]);
  }
}

// ---------------- final 4-way head ----------------
__global__ void pred_kernel(const float* __restrict__ outb,
                            const float* __restrict__ scW,
                            const float* __restrict__ scb,
                            float* __restrict__ pred) {
  int idx = blockIdx.x * blockDim.x + threadIdx.x;
  if (idx >= N_OUT * NDEC) return;
  int t = idx >> 2, e = idx & 3;
  const float* orow = outb + (size_t)t * HID;
  const float* wrow = scW + e * HID;
  float s = 0.f;
#pragma unroll 4
  for (int k = 0; k < HID; k += 4) {
    float4 ov = *(const float4*)(orow + k);
    float4 wv = *(const float4*)(wrow + k);
    s = fmaf(ov.x, wv.x, s);
    s = fmaf(ov.y, wv.y, s);
    s = fmaf(ov.z, wv.z, s);
    s = fmaf(ov.w, wv.w, s);
  }
  pred[idx] = s + scb[e];
}

extern "C" void kernel_launch(void* const* d_in, const int* in_sizes, int n_in,
                              void* d_out, int out_size, void* d_ws, size_t ws_size,
                              hipStream_t stream) {
  if (ws_size < WS_FLOATS * sizeof(float)) return;

  const float* train = (const float*)d_in[0];
  const int*   idxs  = (const int*)d_in[1];
  const float* a0    = (const float*)d_in[2];
  const float* tau_p = (const float*)d_in[3];
  const float* Wih[4] = {(const float*)d_in[4], (const float*)d_in[8],
                         (const float*)d_in[12], (const float*)d_in[16]};
  const float* Whh[4] = {(const float*)d_in[5], (const float*)d_in[9],
                         (const float*)d_in[13], (const float*)d_in[17]};
  const float* bih[4] = {(const float*)d_in[6], (const float*)d_in[10],
                         (const float*)d_in[14], (const float*)d_in[18]};
  const float* bhh[4] = {(const float*)d_in[7], (const float*)d_in[11],
                         (const float*)d_in[15], (const float*)d_in[19]};
  const float* nlW = (const float*)d_in[20];
  const float* nlb = (const float*)d_in[21];
  const float* scW = (const float*)d_in[22];
  const float* scb = (const float*)d_in[23];

  float* ws   = (float*)d_ws;
  float* levs = ws + LEVS_OFF;
  ushort_t* PBW[4]; ushort_t* PBI[4]; float* Bsum[4]; ushort_t* Hb[4];
  for (int lidx = 0; lidx < 4; ++lidx) {
    PBW[lidx]  = (ushort_t*)(ws + PBW_OFF(lidx));
    Bsum[lidx] = ws + BS_OFF(lidx);
    Hb[lidx]   = (ushort_t*)(ws + HB_OFF(lidx));
  }
  PBI[0] = (ushort_t*)(ws + PBI0_OFF);
  for (int lidx = 1; lidx < 4; ++lidx) PBI[lidx] = (ushort_t*)(ws + PBI_OFF(lidx));
  ushort_t* PBnl = (ushort_t*)(ws + PBNL_OFF);
  ushort_t* XPb  = (ushort_t*)(ws + XPB_OFF);
  float* OutF = ws + OUTF_OFF;

  // ---- packing ----
  for (int lidx = 0; lidx < 4; ++lidx)
    hipLaunchKernelGGL(pack_pb_kernel, dim3(1024), dim3(256), 0, stream, Whh[lidx], PBW[lidx], 16);
  hipLaunchKernelGGL(pack_pb_kernel, dim3(512), dim3(256), 0, stream, Wih[0], PBI[0], 8);
  for (int lidx = 1; lidx < 4; ++lidx)
    hipLaunchKernelGGL(pack_pb_kernel, dim3(1024), dim3(256), 0, stream, Wih[lidx], PBI[lidx], 16);
  for (int lidx = 0; lidx < 4; ++lidx)
    hipLaunchKernelGGL(pack_b_kernel, dim3(4), dim3(256), 0, stream, bih[lidx], bhh[lidx], Bsum[lidx]);
  hipLaunchKernelGGL(pack_nl_kernel, dim3(256), dim3(256), 0, stream, nlW, PBnl);

  // ---- levels + act ----
  hipLaunchKernelGGL(levels_kernel, dim3(128), dim3(256), 0, stream, train, idxs, a0, tau_p, levs);
  hipLaunchKernelGGL(act_kernel, dim3(510), dim3(256), 0, stream, train, levs,
                     (float*)d_out + (size_t)N_OUT * NDEC);

  // ---- layer 0: d=1, Sper=4075, 64 WGs x 56 steps ----
  hipLaunchKernelGGL(gemm_win_kernel, dim3(255, 4), dim3(256), 0, stream,
                     train, levs, PBI[0], Bsum[0], XPb);
  hipLaunchKernelGGL(lstm_mfma_kernel, dim3(64), dim3(256), 0, stream,
                     XPb, PBW[0], Hb[0], 1, 4075, 32593);
  // ---- layer 1: d=3, Sper=1359 ----
  hipLaunchKernelGGL(gemm_xp_kernel, dim3(255, 4), dim3(256), 0, stream,
                     Hb[0], PBI[1], Bsum[1], XPb);
  hipLaunchKernelGGL(lstm_mfma_kernel, dim3(64), dim3(256), 0, stream,
                     XPb, PBW[1], Hb[1], 3, 1359, 10865);
  // ---- layer 2: d=6, Sper=680 ----
  hipLaunchKernelGGL(gemm_xp_kernel, dim3(255, 4), dim3(256), 0, stream,
                     Hb[1], PBI[2], Bsum[2], XPb);
  hipLaunchKernelGGL(lstm_mfma_kernel, dim3(64), dim3(256), 0, stream,
                     XPb, PBW[2], Hb[2], 6, 680, 5433);
  // ---- layer 3: d=12, Sper=340 ----
  hipLaunchKernelGGL(gemm_xp_kernel, dim3(255, 4), dim3(256), 0, stream,
                     Hb[2], PBI[3], Bsum[3], XPb);
  hipLaunchKernelGGL(lstm_mfma_kernel, dim3(64), dim3(256), 0, stream,
                     XPb, PBW[3], Hb[3], 12, 340, 2717);

  // ---- epilogue ----
  hipLaunchKernelGGL(gemm_nl_kernel, dim3(255, 2), dim3(256), 0, stream,
                     Hb[1], Hb[3], PBnl, nlb, OutF);
  hipLaunchKernelGGL(pred_kernel, dim3(510), dim3(256), 0, stream,
                     OutF, scW, scb, (float*)d_out);
}

// Round 7
// 7802.626 us; speedup vs baseline: 1.9701x; 1.9701x over previous
//
#include <hip/hip_runtime.h>
#include <cstddef>
#include <cstdint>

#define T_TOTAL 32768
#define IN_SZ   128
#define HID     256
#define G4      1024
#define TA      48
#define TD      12
#define NDEC    4
#define N_WINS  (T_TOTAL - IN_SZ + 1)   // 32641
#define N_OUT   (N_WINS - TA)           // 32593
#define MPAD    32640                   // padded row count (255*128)
#define W48     48
#define P4      4
#define NSTEPS  (W48 + P4)              // 52

// ---------------- workspace layout (float offsets) ----------------
#define LEVS_OFF   ((size_t)0)                                    // 32768
#define PBW_OFF(l) ((size_t)32768 + (size_t)(l)*131072)           // Whh bf16 frags, 4 x 131072
#define PBI0_OFF   ((size_t)557056)                               // Wih0 frags, 65536
#define PBI_OFF(l) ((size_t)622592 + (size_t)((l)-1)*131072)      // Wih1..3 frags
#define PBNL_OFF   ((size_t)1015808)                              // nlW frags, 32768
#define BS_OFF(l)  ((size_t)1048576 + (size_t)(l)*1024)           // 4 x 1024
#define XPB_OFF    ((size_t)1052672)                              // XP bf16 [32640][1024] = 16711680 fl
#define HB_OFF(l)  ((size_t)17764352 + (size_t)(l)*4177920)       // h bf16 [32640][256], 4 x
#define OUTF_OFF   ((size_t)34476032)                             // fp32 [32640][256] = 8355840
#define WS_FLOATS  ((size_t)(34476032 + 8355840))                 // 42831872 (~171 MB)

typedef short s16x8 __attribute__((ext_vector_type(8)));
typedef float f32x16 __attribute__((ext_vector_type(16)));
typedef unsigned short ushort_t;
typedef unsigned int uint_t;

typedef const __attribute__((address_space(1))) unsigned int* as1_u32p;
typedef __attribute__((address_space(3))) unsigned int* as3_u32p;
__device__ __forceinline__ void gload_lds16(const void* g, void* lds) {
  __builtin_amdgcn_global_load_lds((as1_u32p)g, (as3_u32p)lds, 16, 0, 0);
}

__device__ __forceinline__ float sig_fast(float x) {
  return __builtin_amdgcn_rcpf(1.f + __expf(-x));
}
__device__ __forceinline__ float tanh_fast(float x) {
  float ax = fabsf(x);
  float e  = __expf(-2.f * ax);
  float r  = (1.f - e) * __builtin_amdgcn_rcpf(1.f + e);
  return copysignf(r, x);
}
__device__ __forceinline__ ushort_t f2bf(float f) {
  uint_t u = __builtin_bit_cast(uint_t, f);
  uint_t r = (u + 0x7fffu + ((u >> 16) & 1u)) >> 16;
  return (ushort_t)r;
}
__device__ __forceinline__ float bf2f(uint_t us) {
  return __builtin_bit_cast(float, us << 16);
}

// ---------------- levels (contraction, 64-step lookback) ----------------
__global__ void levels_kernel(const float* __restrict__ train,
                              const int* __restrict__ idxs,
                              const float* __restrict__ a0,
                              const float* __restrict__ tau_p,
                              float* __restrict__ levs) {
  int t = blockIdx.x * blockDim.x + threadIdx.x;
  if (t >= T_TOTAL) return;
  int ix   = idxs[0];
  float a  = 1.f / (1.f + __expf(-a0[ix]));
  float fl = tau_p[ix] * 1.0f;
  int q0 = (t >= 64) ? (t - 64) : 0;
  float p = fmaxf(train[q0], fl);
  for (int s = q0 + 1; s <= t; ++s)
    p = fmaxf(a * train[s] + (1.f - a) * p, fl);
  levs[t] = p;
}

// ---------------- act output (exact) ----------------
__global__ void act_kernel(const float* __restrict__ train,
                           const float* __restrict__ levs,
                           float* __restrict__ outp) {
  int idx = blockIdx.x * blockDim.x + threadIdx.x;
  if (idx >= N_OUT * NDEC) return;
  int w = idx >> 2, dec = idx & 3;
  int base = w + IN_SZ + dec * TD;
  float m = train[base];
#pragma unroll
  for (int j = 1; j < TD; ++j) m = fmaxf(m, train[base + j]);
  outp[idx] = m / levs[w + IN_SZ - 1];
}

// ---------------- packing ----------------
// B-frag stream for mfma_f32_32x32x16_bf16 over cols in gate-major packed order:
// global packed col N = wv*256 + g*64 + cp ; frag = wv*(K16*8) + s16*8 + t
// element [l][j]: k = s16*16 + (l>>5)*8 + j ; col-in-block = t*32+(l&31) -> g=t>>1, cp=(t&1)*32+(l&31)
__global__ void pack_pb_kernel(const float* __restrict__ Wsrc, ushort_t* __restrict__ PB, int K16) {
  int idx = blockIdx.x * blockDim.x + threadIdx.x;
  if (idx >= K16 * 16384) return;
  int j = idx & 7;
  int l = (idx >> 3) & 63;
  int frag = idx >> 9;
  int t = frag & 7;
  int s16 = (frag >> 3) % K16;
  int wv  = (frag >> 3) / K16;
  int K = K16 * 16;
  int k = s16 * 16 + ((l >> 5) << 3) + j;
  int g = t >> 1;
  int cp = ((t & 1) << 5) + (l & 31);
  int orow = g * HID + wv * 64 + cp;
  PB[idx] = f2bf(Wsrc[(size_t)orow * K + k]);
}
// nlW frags: natural cols, N=256 as 2 blocks of 128 (4 tiles each)
__global__ void pack_nl_kernel(const float* __restrict__ nlW, ushort_t* __restrict__ PBnl) {
  int idx = blockIdx.x * blockDim.x + threadIdx.x;
  if (idx >= 65536) return;
  int j = idx & 7;
  int l = (idx >> 3) & 63;
  int frag = idx >> 9;
  int t = frag & 3;
  int s16 = (frag >> 2) & 15;
  int nb = frag >> 6;
  int n = nb * 128 + t * 32 + (l & 31);
  int k = s16 * 16 + ((l >> 5) << 3) + j;
  PBnl[idx] = f2bf(nlW[(size_t)n * HID + k]);
}
__global__ void pack_b_kernel(const float* __restrict__ bih, const float* __restrict__ bhh,
                              float* __restrict__ bs) {
  int idx = blockIdx.x * blockDim.x + threadIdx.x;
  if (idx >= G4) return;
  int g = (idx >> 6) & 3;
  int c = ((idx >> 8) << 6) + (idx & 63);
  bs[idx] = bih[g * HID + c] + bhh[g * HID + c];
}

// ---------------- MFMA input-projection GEMM (layers 1-3) ----------------
__global__ __launch_bounds__(256, 1) void gemm_xp_kernel(
    const ushort_t* __restrict__ Ab,   // [MPAD][256] bf16 (h of prev layer)
    const ushort_t* __restrict__ PBih, // frag stream (K16=16)
    const float* __restrict__ Bsum,    // [1024] gate-major packed
    ushort_t* __restrict__ XPb) {      // [MPAD][1024]
  int tid = threadIdx.x;
  int w = tid >> 6, l = tid & 63, hi = l >> 5, lm = l & 31;
  int mb = blockIdx.x, nb = blockIdx.y;
  int m = mb * 128 + w * 32 + lm;
  const s16x8* pbw = ((const s16x8*)PBih) + (size_t)nb * 8192;
  const s16x8* arow = (const s16x8*)(Ab + (size_t)m * 256);
  f32x16 acc[8];
#pragma unroll
  for (int t = 0; t < 8; ++t)
#pragma unroll
    for (int e = 0; e < 16; ++e) acc[t][e] = 0.f;
#pragma unroll
  for (int s16 = 0; s16 < 16; ++s16) {
    s16x8 af = arow[s16 * 2 + hi];
#pragma unroll
    for (int t = 0; t < 8; ++t) {
      s16x8 bf = pbw[(size_t)(s16 * 8 + t) * 64 + l];
      acc[t] = __builtin_amdgcn_mfma_f32_32x32x16_bf16(af, bf, acc[t], 0, 0, 0);
    }
  }
  float bsv[8];
#pragma unroll
  for (int t = 0; t < 8; ++t) bsv[t] = Bsum[nb * 256 + t * 32 + lm];
#pragma unroll
  for (int rr = 0; rr < 16; ++rr) {
    int r  = (rr & 3) + ((rr >> 2) << 3) + (hi << 2);
    int mo = mb * 128 + w * 32 + r;
    if (mo >= N_OUT) continue;
#pragma unroll
    for (int ch = 0; ch < 2; ++ch) {
      uint_t lo = (uint_t)f2bf(acc[0 + ch][rr] + bsv[0 + ch]) |
                  ((uint_t)f2bf(acc[2 + ch][rr] + bsv[2 + ch]) << 16);
      uint_t hi2 = (uint_t)f2bf(acc[4 + ch][rr] + bsv[4 + ch]) |
                   ((uint_t)f2bf(acc[6 + ch][rr] + bsv[6 + ch]) << 16);
      uint64_t v = (uint64_t)lo | ((uint64_t)hi2 << 32);
      __builtin_nontemporal_store(v,
          (uint64_t*)(XPb + (size_t)mo * 1024 + nb * 256 + (ch * 32 + lm) * 4));
    }
  }
}

// ---------------- layer-0 window projection (A built from train/lev) -------
__global__ __launch_bounds__(256, 1) void gemm_win_kernel(
    const float* __restrict__ train, const float* __restrict__ levs,
    const ushort_t* __restrict__ PBih0, // frag stream (K16=8)
    const float* __restrict__ Bsum,
    ushort_t* __restrict__ XPb) {
  int tid = threadIdx.x;
  int w = tid >> 6, l = tid & 63, hi = l >> 5, lm = l & 31;
  int mb = blockIdx.x, nb = blockIdx.y;
  int m = mb * 128 + w * 32 + lm;                 // <= 32639; train reads <= 32766
  float s = 1.f / levs[m + IN_SZ - 1];
  const s16x8* pbw = ((const s16x8*)PBih0) + (size_t)nb * 4096;
  f32x16 acc[8];
#pragma unroll
  for (int t = 0; t < 8; ++t)
#pragma unroll
    for (int e = 0; e < 16; ++e) acc[t][e] = 0.f;
#pragma unroll
  for (int s16 = 0; s16 < 8; ++s16) {
    const float* tp = train + m + s16 * 16 + hi * 8;
    s16x8 af;
#pragma unroll
    for (int j = 0; j < 8; ++j) af[j] = (short)f2bf(tp[j] * s);
#pragma unroll
    for (int t = 0; t < 8; ++t) {
      s16x8 bf = pbw[(size_t)(s16 * 8 + t) * 64 + l];
      acc[t] = __builtin_amdgcn_mfma_f32_32x32x16_bf16(af, bf, acc[t], 0, 0, 0);
    }
  }
  float bsv[8];
#pragma unroll
  for (int t = 0; t < 8; ++t) bsv[t] = Bsum[nb * 256 + t * 32 + lm];
#pragma unroll
  for (int rr = 0; rr < 16; ++rr) {
    int r  = (rr & 3) + ((rr >> 2) << 3) + (hi << 2);
    int mo = mb * 128 + w * 32 + r;
    if (mo >= N_OUT) continue;
#pragma unroll
    for (int ch = 0; ch < 2; ++ch) {
      uint_t lo = (uint_t)f2bf(acc[0 + ch][rr] + bsv[0 + ch]) |
                  ((uint_t)f2bf(acc[2 + ch][rr] + bsv[2 + ch]) << 16);
      uint_t hi2 = (uint_t)f2bf(acc[4 + ch][rr] + bsv[4 + ch]) |
                   ((uint_t)f2bf(acc[6 + ch][rr] + bsv[6 + ch]) << 16);
      uint64_t v = (uint64_t)lo | ((uint64_t)hi2 << 32);
      __builtin_nontemporal_store(v,
          (uint64_t*)(XPb + (size_t)mo * 1024 + nb * 256 + (ch * 32 + lm) * 4));
    }
  }
}

// ---------------- MFMA segment-parallel LSTM (v5: resident weights) --------
// 255 WGs x 4 waves, M=32 chains/WG, P=4, W=48. Wave w owns packed cols
// [w*256,(w+1)*256). Weight k-chunks (s16 of 16): 0-7 in VGPRs (256 regs),
// 8-11 in LDS (128 KB, loaded once), 12-15 streamed from L2 per step,
// interleaved so latency hides under resident MFMAs.
__global__ __launch_bounds__(256, 1) void lstm_mfma_kernel(
    const ushort_t* __restrict__ XPb,  // [MPAD][1024] bf16 gate-packed
    const ushort_t* __restrict__ PBu,  // Whh frag stream
    ushort_t* __restrict__ Hb,         // [MPAD][256] bf16
    int d, int Sper, int L) {
  __shared__ ushort_t Abuf[32][264];   // 16.9 KB
  __shared__ ushort_t Bl[65536];       // 128 KB: [w][s16-8][t] 1KB blocks
  const int tid = threadIdx.x;
  const int w  = tid >> 6;
  const int l  = tid & 63;
  const int hi = l >> 5;
  const int lm = l & 31;

  for (int idx = tid; idx < 32 * 264; idx += 256) ((ushort_t*)Abuf)[idx] = 0;

  int meta[16];
#pragma unroll
  for (int rr = 0; rr < 16; ++rr) {
    int r  = (rr & 3) + ((rr >> 2) << 3) + (hi << 2);
    int id = blockIdx.x * 32 + r;
    int dl = id / Sper;
    int s  = id - dl * Sper;
    int p0 = (dl >= d) ? L : s * P4;   // sentinel: never writes (q>=p0 false)
    int ds = (dl >= d) ? 0 : dl;
    meta[rr] = p0 | (ds << 20);
  }
  float cst[32];
#pragma unroll
  for (int z = 0; z < 32; ++z) cst[z] = 0.f;

  // per-lane global base of this wave's frag stream (frag b = (w*128+b), 1KB each)
  const char* pbase = (const char*)PBu + ((size_t)w << 17) + (size_t)l * 16;

  // resident VGPR weights: s16 0..7
  s16x8 bwv[8][8];
#pragma unroll
  for (int s16 = 0; s16 < 8; ++s16)
#pragma unroll
    for (int t = 0; t < 8; ++t)
      bwv[s16][t] = *(const s16x8*)(pbase + (size_t)(s16 * 8 + t) * 1024);

  // LDS-resident weights: s16 8..11 (one-time DMA)
  ushort_t* blw = Bl + w * 16384;      // 32 KB per wave
#pragma unroll
  for (int c = 0; c < 32; ++c)
    gload_lds16(pbase + (size_t)(64 + c) * 1024, blw + c * 512);
  asm volatile("s_waitcnt vmcnt(0)" ::: "memory");
  __syncthreads();

#pragma unroll 1
  for (int i = 0; i < NSTEPS; ++i) {
    f32x16 acc[8];
#pragma unroll
    for (int t = 0; t < 8; ++t)
#pragma unroll
      for (int e = 0; e < 16; ++e) acc[t][e] = 0.f;

    s16x8 sv[8];
#define LOADS(s16v)                                                        \
    _Pragma("unroll")                                                      \
    for (int t = 0; t < 8; ++t)                                            \
      sv[t] = *(const s16x8*)(pbase + (size_t)((s16v) * 8 + t) * 1024);
#define AFRAG(s16v) (*(const s16x8*)&Abuf[lm][(s16v) * 16 + hi * 8])
#define MFMA8(bsrc)                                                        \
    _Pragma("unroll")                                                      \
    for (int t = 0; t < 8; ++t)                                            \
      acc[t] = __builtin_amdgcn_mfma_f32_32x32x16_bf16(af, (bsrc), acc[t], 0, 0, 0);

    LOADS(12)
#pragma unroll
    for (int s16 = 0; s16 < 8; ++s16) {
      s16x8 af = AFRAG(s16);
      MFMA8(bwv[s16][t])
    }
    {
      s16x8 af = AFRAG(12);
      MFMA8(sv[t])
    }
    LOADS(13)
#pragma unroll
    for (int s16 = 8; s16 < 10; ++s16) {
      s16x8 af = AFRAG(s16);
#pragma unroll
      for (int t = 0; t < 8; ++t) {
        s16x8 bf = *(const s16x8*)(blw + ((s16 - 8) * 8 + t) * 512 + l * 8);
        acc[t] = __builtin_amdgcn_mfma_f32_32x32x16_bf16(af, bf, acc[t], 0, 0, 0);
      }
    }
    {
      s16x8 af = AFRAG(13);
      MFMA8(sv[t])
    }
    LOADS(14)
#pragma unroll
    for (int s16 = 10; s16 < 12; ++s16) {
      s16x8 af = AFRAG(s16);
#pragma unroll
      for (int t = 0; t < 8; ++t) {
        s16x8 bf = *(const s16x8*)(blw + ((s16 - 8) * 8 + t) * 512 + l * 8);
        acc[t] = __builtin_amdgcn_mfma_f32_32x32x16_bf16(af, bf, acc[t], 0, 0, 0);
      }
    }
    {
      s16x8 af = AFRAG(14);
      MFMA8(sv[t])
    }
    LOADS(15)
    {
      s16x8 af = AFRAG(15);
      MFMA8(sv[t])
    }
#undef LOADS
#undef AFRAG
#undef MFMA8
    __syncthreads();   // A-frag reads done before Abuf rewrite

    // ---- gate phase: lane-local i,f,g,o ----
#pragma unroll
    for (int rr = 0; rr < 16; ++rr) {
      int mv = meta[rr];
      int p0 = mv & 0xFFFFF;
      int dl = mv >> 20;
      int q0 = p0 - W48; if (q0 < 0) q0 = 0;
      int q  = q0 + i;
      int p1 = p0 + P4; if (p1 > L) p1 = L;
      int t  = q * d + dl;
      bool valid = (q < p1) && (t < N_OUT);
      int r  = (rr & 3) + ((rr >> 2) << 3) + (hi << 2);
#pragma unroll
      for (int ch = 0; ch < 2; ++ch) {
        uint64_t xi64 = 0;
        if (valid)
          xi64 = __builtin_nontemporal_load(
              (const uint64_t*)(XPb + (size_t)t * 1024 + w * 256 + (ch * 32 + lm) * 4));
        uint_t xlo = (uint_t)xi64;
        uint_t xhi = (uint_t)(xi64 >> 32);
        float pi = acc[0 + ch][rr] + bf2f(xlo & 0xffffu);
        float pf = acc[2 + ch][rr] + bf2f(xlo >> 16);
        float pg = acc[4 + ch][rr] + bf2f(xhi & 0xffffu);
        float po = acc[6 + ch][rr] + bf2f(xhi >> 16);
        float hh = 0.f;
        if (valid) {
          float cs = sig_fast(pf) * cst[rr * 2 + ch] + sig_fast(pi) * tanh_fast(pg);
          cst[rr * 2 + ch] = cs;
          hh = sig_fast(po) * tanh_fast(cs);
          if (q >= p0)
            __builtin_nontemporal_store(f2bf(hh),
                Hb + (size_t)t * HID + w * 64 + ch * 32 + lm);
        }
        Abuf[r][w * 64 + ch * 32 + lm] = f2bf(hh);
      }
    }
    __syncthreads();
  }
}

// ---------------- epilogue: out = tanh((H1+H3) @ nlW^T + nlb), fp32 --------
__global__ __launch_bounds__(256, 2) void gemm_nl_kernel(
    const ushort_t* __restrict__ H1b, const ushort_t* __restrict__ H3b,
    const ushort_t* __restrict__ PBnl, const float* __restrict__ nlb,
    float* __restrict__ OutF) {
  int tid = threadIdx.x;
  int w = tid >> 6, l = tid & 63, hi = l >> 5, lm = l & 31;
  int mb = blockIdx.x, nb = blockIdx.y;
  int m = mb * 128 + w * 32 + lm;
  const s16x8* pbn = ((const s16x8*)PBnl) + (size_t)nb * 4096;
  const s16x8* a1 = (const s16x8*)(H1b + (size_t)m * 256);
  const s16x8* a3 = (const s16x8*)(H3b + (size_t)m * 256);
  f32x16 acc[4];
#pragma unroll
  for (int t = 0; t < 4; ++t)
#pragma unroll
    for (int e = 0; e < 16; ++e) acc[t][e] = 0.f;
#pragma unroll
  for (int s16 = 0; s16 < 16; ++s16) {
    s16x8 af1 = a1[s16 * 2 + hi];
    s16x8 af3 = a3[s16 * 2 + hi];
#pragma unroll
    for (int t = 0; t < 4; ++t) {
      s16x8 bf = pbn[(size_t)(s16 * 4 + t) * 64 + l];
      acc[t] = __builtin_amdgcn_mfma_f32_32x32x16_bf16(af1, bf, acc[t], 0, 0, 0);
      acc[t] = __builtin_amdgcn_mfma_f32_32x32x16_bf16(af3, bf, acc[t], 0, 0, 0);
    }
  }
  float bb[4];
#pragma unroll
  for (int t = 0; t < 4; ++t) bb[t] = nlb[nb * 128 + t * 32 + lm];
#pragma unroll
  for (int rr = 0; rr < 16; ++rr) {
    int r  = (rr & 3) + ((rr >> 2) << 3) + (hi << 2);
    int mo = mb * 128 + w * 32 + r;
    if (mo >= N_OUT) continue;
#pragma unroll
    for (int t = 0; t < 4; ++t)
      OutF[(size_t)mo * 256 + nb * 128 + t * 32 + lm] = tanh_fast(acc[t][rr] + bb[t]);
  }
}

// ---------------- final 4-way head ----------------
__global__ void pred_kernel(const float* __restrict__ outb,
                            const float* __restrict__ scW,
                            const float* __restrict__ scb,
                            float* __restrict__ pred) {
  int idx = blockIdx.x * blockDim.x + threadIdx.x;
  if (idx >= N_OUT * NDEC) return;
  int t = idx >> 2, e = idx & 3;
  const float* orow = outb + (size_t)t * HID;
  const float* wrow = scW + e * HID;
  float s = 0.f;
#pragma unroll 4
  for (int k = 0; k < HID; k += 4) {
    float4 ov = *(const float4*)(orow + k);
    float4 wv = *(const float4*)(wrow + k);
    s = fmaf(ov.x, wv.x, s);
    s = fmaf(ov.y, wv.y, s);
    s = fmaf(ov.z, wv.z, s);
    s = fmaf(ov.w, wv.w, s);
  }
  pred[idx] = s + scb[e];
}

extern "C" void kernel_launch(void* const* d_in, const int* in_sizes, int n_in,
                              void* d_out, int out_size, void* d_ws, size_t ws_size,
                              hipStream_t stream) {
  if (ws_size < WS_FLOATS * sizeof(float)) return;

  const float* train = (const float*)d_in[0];
  const int*   idxs  = (const int*)d_in[1];
  const float* a0    = (const float*)d_in[2];
  const float* tau_p = (const float*)d_in[3];
  const float* Wih[4] = {(const float*)d_in[4], (const float*)d_in[8],
                         (const float*)d_in[12], (const float*)d_in[16]};
  const float* Whh[4] = {(const float*)d_in[5], (const float*)d_in[9],
                         (const float*)d_in[13], (const float*)d_in[17]};
  const float* bih[4] = {(const float*)d_in[6], (const float*)d_in[10],
                         (const float*)d_in[14], (const float*)d_in[18]};
  const float* bhh[4] = {(const float*)d_in[7], (const float*)d_in[11],
                         (const float*)d_in[15], (const float*)d_in[19]};
  const float* nlW = (const float*)d_in[20];
  const float* nlb = (const float*)d_in[21];
  const float* scW = (const float*)d_in[22];
  const float* scb = (const float*)d_in[23];

  float* ws   = (float*)d_ws;
  float* levs = ws + LEVS_OFF;
  ushort_t* PBW[4]; ushort_t* PBI[4]; float* Bsum[4]; ushort_t* Hb[4];
  for (int lidx = 0; lidx < 4; ++lidx) {
    PBW[lidx]  = (ushort_t*)(ws + PBW_OFF(lidx));
    Bsum[lidx] = ws + BS_OFF(lidx);
    Hb[lidx]   = (ushort_t*)(ws + HB_OFF(lidx));
  }
  PBI[0] = (ushort_t*)(ws + PBI0_OFF);
  for (int lidx = 1; lidx < 4; ++lidx) PBI[lidx] = (ushort_t*)(ws + PBI_OFF(lidx));
  ushort_t* PBnl = (ushort_t*)(ws + PBNL_OFF);
  ushort_t* XPb  = (ushort_t*)(ws + XPB_OFF);
  float* OutF = ws + OUTF_OFF;

  // ---- packing ----
  for (int lidx = 0; lidx < 4; ++lidx)
    hipLaunchKernelGGL(pack_pb_kernel, dim3(1024), dim3(256), 0, stream, Whh[lidx], PBW[lidx], 16);
  hipLaunchKernelGGL(pack_pb_kernel, dim3(512), dim3(256), 0, stream, Wih[0], PBI[0], 8);
  for (int lidx = 1; lidx < 4; ++lidx)
    hipLaunchKernelGGL(pack_pb_kernel, dim3(1024), dim3(256), 0, stream, Wih[lidx], PBI[lidx], 16);
  for (int lidx = 0; lidx < 4; ++lidx)
    hipLaunchKernelGGL(pack_b_kernel, dim3(4), dim3(256), 0, stream, bih[lidx], bhh[lidx], Bsum[lidx]);
  hipLaunchKernelGGL(pack_nl_kernel, dim3(256), dim3(256), 0, stream, nlW, PBnl);

  // ---- levels + act ----
  hipLaunchKernelGGL(levels_kernel, dim3(128), dim3(256), 0, stream, train, idxs, a0, tau_p, levs);
  hipLaunchKernelGGL(act_kernel, dim3(510), dim3(256), 0, stream, train, levs,
                     (float*)d_out + (size_t)N_OUT * NDEC);

  // ---- layer 0: d=1, Sper=8149 ----
  hipLaunchKernelGGL(gemm_win_kernel, dim3(255, 4), dim3(256), 0, stream,
                     train, levs, PBI[0], Bsum[0], XPb);
  hipLaunchKernelGGL(lstm_mfma_kernel, dim3(255), dim3(256), 0, stream,
                     XPb, PBW[0], Hb[0], 1, 8149, 32593);
  // ---- layer 1: d=3, Sper=2717 ----
  hipLaunchKernelGGL(gemm_xp_kernel, dim3(255, 4), dim3(256), 0, stream,
                     Hb[0], PBI[1], Bsum[1], XPb);
  hipLaunchKernelGGL(lstm_mfma_kernel, dim3(255), dim3(256), 0, stream,
                     XPb, PBW[1], Hb[1], 3, 2717, 10865);
  // ---- layer 2: d=6, Sper=1359 ----
  hipLaunchKernelGGL(gemm_xp_kernel, dim3(255, 4), dim3(256), 0, stream,
                     Hb[1], PBI[2], Bsum[2], XPb);
  hipLaunchKernelGGL(lstm_mfma_kernel, dim3(255), dim3(256), 0, stream,
                     XPb, PBW[2], Hb[2], 6, 1359, 5433);
  // ---- layer 3: d=12, Sper=680 ----
  hipLaunchKernelGGL(gemm_xp_kernel, dim3(255, 4), dim3(256), 0, stream,
                     Hb[2], PBI[3], Bsum[3], XPb);
  hipLaunchKernelGGL(lstm_mfma_kernel, dim3(255), dim3(256), 0, stream,
                     XPb, PBW[3], Hb[3], 12, 680, 2717);

  // ---- epilogue ----
  hipLaunchKernelGGL(gemm_nl_kernel, dim3(255, 2), dim3(256), 0, stream,
                     Hb[1], Hb[3], PBnl, nlb, OutF);
  hipLaunchKernelGGL(pred_kernel, dim3(510), dim3(256), 0, stream,
                     OutF, scW, scb, (float*)d_out);
}

// Round 8
// 6193.682 us; speedup vs baseline: 2.4819x; 1.2598x over previous
//
#include <hip/hip_runtime.h>
#include <cstddef>
#include <cstdint>

#define T_TOTAL 32768
#define IN_SZ   128
#define HID     256
#define G4      1024
#define TA      48
#define TD      12
#define NDEC    4
#define N_WINS  (T_TOTAL - IN_SZ + 1)   // 32641
#define N_OUT   (N_WINS - TA)           // 32593
#define MPAD    32640                   // padded row count (255*128)
#define W48     48
#define P4      4
#define NSTEPS  (W48 + P4)              // 52

// ---------------- workspace layout (float offsets) ----------------
#define LEVS_OFF   ((size_t)0)                                    // 32768
#define PBW8_OFF(l) ((size_t)32768 + (size_t)(l)*65536)           // Whh int8 frags, 4 x 256KB
#define SC_OFF     ((size_t)294912)                               // 16 scale slots
#define PBI0_OFF   ((size_t)294928)                               // Wih0 bf16 frags, 65536
#define PBI_OFF(l) ((size_t)360464 + (size_t)((l)-1)*131072)      // Wih1..3 bf16 frags
#define PBNL_OFF   ((size_t)753680)                               // nlW frags, 32768
#define BS_OFF(l)  ((size_t)786448 + (size_t)(l)*1024)            // 4 x 1024
#define XPB_OFF    ((size_t)790544)                               // XP bf16 [32640][1024] = 16711680 fl
#define HB_OFF(l)  ((size_t)17502224 + (size_t)(l)*4177920)       // h bf16 [32640][256], 4 x
#define OUTF_OFF   ((size_t)34213904)                             // fp32 [32640][256] = 8355840
#define WS_FLOATS  ((size_t)(34213904 + 8355840))                 // 42569744 (~170 MB)

typedef short s16x8 __attribute__((ext_vector_type(8)));
typedef float f32x16 __attribute__((ext_vector_type(16)));
typedef int   i32x16 __attribute__((ext_vector_type(16)));
typedef unsigned short ushort_t;
typedef unsigned int uint_t;

typedef const __attribute__((address_space(1))) unsigned int* as1_u32p;
typedef __attribute__((address_space(3))) unsigned int* as3_u32p;
__device__ __forceinline__ void gload_lds16(const void* g, void* lds) {
  __builtin_amdgcn_global_load_lds((as1_u32p)g, (as3_u32p)lds, 16, 0, 0);
}

__device__ __forceinline__ float sig_fast(float x) {
  return __builtin_amdgcn_rcpf(1.f + __expf(-x));
}
__device__ __forceinline__ float tanh_fast(float x) {
  float ax = fabsf(x);
  float e  = __expf(-2.f * ax);
  float r  = (1.f - e) * __builtin_amdgcn_rcpf(1.f + e);
  return copysignf(r, x);
}
__device__ __forceinline__ ushort_t f2bf(float f) {
  uint_t u = __builtin_bit_cast(uint_t, f);
  uint_t r = (u + 0x7fffu + ((u >> 16) & 1u)) >> 16;
  return (ushort_t)r;
}
__device__ __forceinline__ float bf2f(uint_t us) {
  return __builtin_bit_cast(float, us << 16);
}

// ---------------- levels (contraction, 64-step lookback) ----------------
__global__ void levels_kernel(const float* __restrict__ train,
                              const int* __restrict__ idxs,
                              const float* __restrict__ a0,
                              const float* __restrict__ tau_p,
                              float* __restrict__ levs) {
  int t = blockIdx.x * blockDim.x + threadIdx.x;
  if (t >= T_TOTAL) return;
  int ix   = idxs[0];
  float a  = 1.f / (1.f + __expf(-a0[ix]));
  float fl = tau_p[ix] * 1.0f;
  int q0 = (t >= 64) ? (t - 64) : 0;
  float p = fmaxf(train[q0], fl);
  for (int s = q0 + 1; s <= t; ++s)
    p = fmaxf(a * train[s] + (1.f - a) * p, fl);
  levs[t] = p;
}

// ---------------- act output (exact) ----------------
__global__ void act_kernel(const float* __restrict__ train,
                           const float* __restrict__ levs,
                           float* __restrict__ outp) {
  int idx = blockIdx.x * blockDim.x + threadIdx.x;
  if (idx >= N_OUT * NDEC) return;
  int w = idx >> 2, dec = idx & 3;
  int base = w + IN_SZ + dec * TD;
  float m = train[base];
#pragma unroll
  for (int j = 1; j < TD; ++j) m = fmaxf(m, train[base + j]);
  outp[idx] = m / levs[w + IN_SZ - 1];
}

// ---------------- scale slots ----------------
__global__ void zero_sc_kernel(uint_t* __restrict__ sc) {
  if (threadIdx.x < 16) sc[threadIdx.x] = 0u;
}
__global__ void wmax_kernel(const float* __restrict__ W, uint_t* __restrict__ slot) {
  __shared__ float red[256];
  int tid = threadIdx.x;
  float m = 0.f;
  for (int i = blockIdx.x * 256 + tid; i < HID * G4; i += gridDim.x * 256)
    m = fmaxf(m, fabsf(W[i]));
  red[tid] = m;
  __syncthreads();
  for (int s = 128; s > 0; s >>= 1) {
    if (tid < s) red[tid] = fmaxf(red[tid], red[tid + s]);
    __syncthreads();
  }
  if (tid == 0) atomicMax(slot, __float_as_uint(red[0]));
}

// ---------------- packing ----------------
// bf16 B-frag stream (Wih / generic): same geometry as mfma 32x32x16 bf16.
// global packed col N = wv*256 + g*64 + cp ; frag = wv*(K16*8) + s16*8 + t
// element [l][j]: k = s16*16 + (l>>5)*8 + j ; col-in-block = t*32+(l&31) -> g=t>>1, cp=(t&1)*32+(l&31)
__global__ void pack_pb_kernel(const float* __restrict__ Wsrc, ushort_t* __restrict__ PB, int K16) {
  int idx = blockIdx.x * blockDim.x + threadIdx.x;
  if (idx >= K16 * 16384) return;
  int j = idx & 7;
  int l = (idx >> 3) & 63;
  int frag = idx >> 9;
  int t = frag & 7;
  int s16 = (frag >> 3) % K16;
  int wv  = (frag >> 3) / K16;
  int K = K16 * 16;
  int k = s16 * 16 + ((l >> 5) << 3) + j;
  int g = t >> 1;
  int cp = ((t & 1) << 5) + (l & 31);
  int orow = g * HID + wv * 64 + cp;
  PB[idx] = f2bf(Wsrc[(size_t)orow * K + k]);
}
// int8 B-frag stream for Whh (mfma_i32_32x32x16_i8, same frag geometry)
__global__ void pack_pbw8_kernel(const float* __restrict__ Whh, char* __restrict__ PB8,
                                 const uint_t* __restrict__ slot) {
  int idx = blockIdx.x * blockDim.x + threadIdx.x;
  if (idx >= 262144) return;
  float inv = 127.f / __uint_as_float(slot[0]);
  int j = idx & 7;
  int l = (idx >> 3) & 63;
  int frag = idx >> 9;
  int t = frag & 7;
  int s16 = (frag >> 3) & 15;
  int wv  = frag >> 7;
  int k = s16 * 16 + ((l >> 5) << 3) + j;
  int g = t >> 1;
  int cp = ((t & 1) << 5) + (l & 31);
  int orow = g * HID + wv * 64 + cp;
  float q = rintf(Whh[(size_t)orow * HID + k] * inv);
  q = fmaxf(-127.f, fminf(127.f, q));
  PB8[idx] = (char)(int)q;
}
// nlW frags: natural cols, N=256 as 2 blocks of 128 (4 tiles each)
__global__ void pack_nl_kernel(const float* __restrict__ nlW, ushort_t* __restrict__ PBnl) {
  int idx = blockIdx.x * blockDim.x + threadIdx.x;
  if (idx >= 65536) return;
  int j = idx & 7;
  int l = (idx >> 3) & 63;
  int frag = idx >> 9;
  int t = frag & 3;
  int s16 = (frag >> 2) & 15;
  int nb = frag >> 6;
  int n = nb * 128 + t * 32 + (l & 31);
  int k = s16 * 16 + ((l >> 5) << 3) + j;
  PBnl[idx] = f2bf(nlW[(size_t)n * HID + k]);
}
__global__ void pack_b_kernel(const float* __restrict__ bih, const float* __restrict__ bhh,
                              float* __restrict__ bs) {
  int idx = blockIdx.x * blockDim.x + threadIdx.x;
  if (idx >= G4) return;
  int g = (idx >> 6) & 3;
  int c = ((idx >> 8) << 6) + (idx & 63);
  bs[idx] = bih[g * HID + c] + bhh[g * HID + c];
}

// ---------------- MFMA input-projection GEMM (layers 1-3) ----------------
__global__ __launch_bounds__(256, 1) void gemm_xp_kernel(
    const ushort_t* __restrict__ Ab,   // [MPAD][256] bf16 (h of prev layer)
    const ushort_t* __restrict__ PBih, // frag stream (K16=16)
    const float* __restrict__ Bsum,    // [1024] gate-major packed
    ushort_t* __restrict__ XPb) {      // [MPAD][1024]
  int tid = threadIdx.x;
  int w = tid >> 6, l = tid & 63, hi = l >> 5, lm = l & 31;
  int mb = blockIdx.x, nb = blockIdx.y;
  int m = mb * 128 + w * 32 + lm;
  const s16x8* pbw = ((const s16x8*)PBih) + (size_t)nb * 8192;
  const s16x8* arow = (const s16x8*)(Ab + (size_t)m * 256);
  f32x16 acc[8];
#pragma unroll
  for (int t = 0; t < 8; ++t)
#pragma unroll
    for (int e = 0; e < 16; ++e) acc[t][e] = 0.f;
#pragma unroll
  for (int s16 = 0; s16 < 16; ++s16) {
    s16x8 af = arow[s16 * 2 + hi];
#pragma unroll
    for (int t = 0; t < 8; ++t) {
      s16x8 bf = pbw[(size_t)(s16 * 8 + t) * 64 + l];
      acc[t] = __builtin_amdgcn_mfma_f32_32x32x16_bf16(af, bf, acc[t], 0, 0, 0);
    }
  }
  float bsv[8];
#pragma unroll
  for (int t = 0; t < 8; ++t) bsv[t] = Bsum[nb * 256 + t * 32 + lm];
#pragma unroll
  for (int rr = 0; rr < 16; ++rr) {
    int r  = (rr & 3) + ((rr >> 2) << 3) + (hi << 2);
    int mo = mb * 128 + w * 32 + r;
    if (mo >= N_OUT) continue;
#pragma unroll
    for (int ch = 0; ch < 2; ++ch) {
      uint_t lo = (uint_t)f2bf(acc[0 + ch][rr] + bsv[0 + ch]) |
                  ((uint_t)f2bf(acc[2 + ch][rr] + bsv[2 + ch]) << 16);
      uint_t hi2 = (uint_t)f2bf(acc[4 + ch][rr] + bsv[4 + ch]) |
                   ((uint_t)f2bf(acc[6 + ch][rr] + bsv[6 + ch]) << 16);
      uint64_t v = (uint64_t)lo | ((uint64_t)hi2 << 32);
      __builtin_nontemporal_store(v,
          (uint64_t*)(XPb + (size_t)mo * 1024 + nb * 256 + (ch * 32 + lm) * 4));
    }
  }
}

// ---------------- layer-0 window projection (A built from train/lev) -------
__global__ __launch_bounds__(256, 1) void gemm_win_kernel(
    const float* __restrict__ train, const float* __restrict__ levs,
    const ushort_t* __restrict__ PBih0, // frag stream (K16=8)
    const float* __restrict__ Bsum,
    ushort_t* __restrict__ XPb) {
  int tid = threadIdx.x;
  int w = tid >> 6, l = tid & 63, hi = l >> 5, lm = l & 31;
  int mb = blockIdx.x, nb = blockIdx.y;
  int m = mb * 128 + w * 32 + lm;                 // <= 32639; train reads <= 32766
  float s = 1.f / levs[m + IN_SZ - 1];
  const s16x8* pbw = ((const s16x8*)PBih0) + (size_t)nb * 4096;
  f32x16 acc[8];
#pragma unroll
  for (int t = 0; t < 8; ++t)
#pragma unroll
    for (int e = 0; e < 16; ++e) acc[t][e] = 0.f;
#pragma unroll
  for (int s16 = 0; s16 < 8; ++s16) {
    const float* tp = train + m + s16 * 16 + hi * 8;
    s16x8 af;
#pragma unroll
    for (int j = 0; j < 8; ++j) af[j] = (short)f2bf(tp[j] * s);
#pragma unroll
    for (int t = 0; t < 8; ++t) {
      s16x8 bf = pbw[(size_t)(s16 * 8 + t) * 64 + l];
      acc[t] = __builtin_amdgcn_mfma_f32_32x32x16_bf16(af, bf, acc[t], 0, 0, 0);
    }
  }
  float bsv[8];
#pragma unroll
  for (int t = 0; t < 8; ++t) bsv[t] = Bsum[nb * 256 + t * 32 + lm];
#pragma unroll
  for (int rr = 0; rr < 16; ++rr) {
    int r  = (rr & 3) + ((rr >> 2) << 3) + (hi << 2);
    int mo = mb * 128 + w * 32 + r;
    if (mo >= N_OUT) continue;
#pragma unroll
    for (int ch = 0; ch < 2; ++ch) {
      uint_t lo = (uint_t)f2bf(acc[0 + ch][rr] + bsv[0 + ch]) |
                  ((uint_t)f2bf(acc[2 + ch][rr] + bsv[2 + ch]) << 16);
      uint_t hi2 = (uint_t)f2bf(acc[4 + ch][rr] + bsv[4 + ch]) |
                   ((uint_t)f2bf(acc[6 + ch][rr] + bsv[6 + ch]) << 16);
      uint64_t v = (uint64_t)lo | ((uint64_t)hi2 << 32);
      __builtin_nontemporal_store(v,
          (uint64_t*)(XPb + (size_t)mo * 1024 + nb * 256 + (ch * 32 + lm) * 4));
    }
  }
}

// ---------------- MFMA segment-parallel LSTM (v6: int8 resident + LDS XP) --
// 255 WGs x 4 waves, M=32 chains/WG, P=4, W=48. Whh int8 fully VGPR-resident
// (256 regs/wave). XP rows double-buffered into LDS via global_load_lds,
// issued at top of MFMA phase for step i+1 (latency hidden under MFMAs).
__global__ __launch_bounds__(256, 1) void lstm_mfma_kernel(
    const ushort_t* __restrict__ XPb,  // [MPAD][1024] bf16 gate-packed
    const char* __restrict__ PB8,      // Whh int8 frag stream
    const uint_t* __restrict__ slot,   // absmax slot
    ushort_t* __restrict__ Hb,         // [MPAD][256] bf16
    int d, int Sper, int L) {
  __shared__ char Abuf[32][264];            // 8.4 KB (h as int8)
  __shared__ ushort_t XPs[2][32][1024];     // 128 KB
  const int tid = threadIdx.x;
  const int w  = tid >> 6;
  const int l  = tid & 63;
  const int hi = l >> 5;
  const int lm = l & 31;

  for (int idx = tid; idx < 32 * 264; idx += 256) (&Abuf[0][0])[idx] = 0;

  const float Sf = __uint_as_float(slot[0]) * (1.f / (127.f * 127.f));

  // gate-phase chain meta (per-thread, 16 chains of this (rr,hi) set)
  int meta[16];
#pragma unroll
  for (int rr = 0; rr < 16; ++rr) {
    int r  = (rr & 3) + ((rr >> 2) << 3) + (hi << 2);
    int id = blockIdx.x * 32 + r;
    int dl = id / Sper;
    int s  = id - dl * Sper;
    int p0 = (dl >= d) ? L : s * P4;   // sentinel: never writes (q>=p0 false)
    int ds = (dl >= d) ? 0 : dl;
    meta[rr] = p0 | (ds << 20);
  }
  float cst[32];
#pragma unroll
  for (int z = 0; z < 32; ++z) cst[z] = 0.f;

  // staging meta for this wave's 8 rows (wave-uniform -> SGPR)
  int tb[8], tc[8];
#pragma unroll
  for (int j = 0; j < 8; ++j) {
    int r  = w * 8 + j;
    int id = blockIdx.x * 32 + r;
    int dl = id / Sper;
    int s  = id - dl * Sper;
    int p0 = (dl >= d) ? L : s * P4;
    int ds = (dl >= d) ? 0 : dl;
    int q0 = p0 - W48; if (q0 < 0) q0 = 0;
    int p1 = p0 + P4; if (p1 > L) p1 = L;
    int tmax = (p1 - 1) * d + ds;
    if (tmax > N_OUT - 1) tmax = N_OUT - 1;
    tb[j] = __builtin_amdgcn_readfirstlane(q0 * d + ds);
    tc[j] = __builtin_amdgcn_readfirstlane(tmax);
  }

  // resident int8 weights: 16 k-chunks x 8 tiles x 8B = 256 VGPRs
  long wq[16][8];
  {
    const char* pw = PB8 + ((size_t)w << 16) + (size_t)l * 8;
#pragma unroll
    for (int s16 = 0; s16 < 16; ++s16)
#pragma unroll
      for (int t = 0; t < 8; ++t)
        wq[s16][t] = *(const long*)(pw + (size_t)(s16 * 8 + t) * 512);
  }

  // prologue: stage step 0 XP rows into buf 0
#pragma unroll
  for (int j = 0; j < 8; ++j) {
    int t0 = tb[j]; if (t0 > tc[j]) t0 = tc[j];
    const char* src = (const char*)XPb + (size_t)t0 * 2048 + (size_t)l * 16;
    gload_lds16(src,        (char*)&XPs[0][w * 8 + j][0]);
    gload_lds16(src + 1024, (char*)&XPs[0][w * 8 + j][512]);
  }
  __syncthreads();   // drains vmcnt (DMA) before first use

#pragma unroll 1
  for (int i = 0; i < NSTEPS; ++i) {
    // stage step i+1 into buf (i+1)&1 (overlaps with MFMA phase)
    if (i + 1 < NSTEPS) {
      const int nbuf = (i + 1) & 1;
#pragma unroll
      for (int j = 0; j < 8; ++j) {
        int t = tb[j] + (i + 1) * d;
        if (t > tc[j]) t = tc[j];
        const char* src = (const char*)XPb + (size_t)t * 2048 + (size_t)l * 16;
        gload_lds16(src,        (char*)&XPs[nbuf][w * 8 + j][0]);
        gload_lds16(src + 1024, (char*)&XPs[nbuf][w * 8 + j][512]);
      }
    }

    // MFMA phase: preacts from resident weights + Abuf
    i32x16 acc[8];
#pragma unroll
    for (int t = 0; t < 8; ++t)
#pragma unroll
      for (int e = 0; e < 16; ++e) acc[t][e] = 0;
#pragma unroll
    for (int s16 = 0; s16 < 16; ++s16) {
      long af = *(const long*)&Abuf[lm][s16 * 16 + hi * 8];
#pragma unroll
      for (int t = 0; t < 8; ++t)
        acc[t] = __builtin_amdgcn_mfma_i32_32x32x16_i8(af, wq[s16][t], acc[t], 0, 0, 0);
    }
    __syncthreads();   // Abuf reads done; DMA for i+1 drained (full waitcnt)

    // gate phase: lane-local i,f,g,o; XP from LDS
    const int buf = i & 1;
#pragma unroll
    for (int rr = 0; rr < 16; ++rr) {
      int mv = meta[rr];
      int p0 = mv & 0xFFFFF;
      int dl = mv >> 20;
      int q0 = p0 - W48; if (q0 < 0) q0 = 0;
      int q  = q0 + i;
      int p1 = p0 + P4; if (p1 > L) p1 = L;
      int t  = q * d + dl;
      bool valid = (q < p1) && (t < N_OUT);
      int r  = (rr & 3) + ((rr >> 2) << 3) + (hi << 2);
#pragma unroll
      for (int ch = 0; ch < 2; ++ch) {
        uint64_t xi64 = *(const uint64_t*)&XPs[buf][r][w * 256 + (ch * 32 + lm) * 4];
        uint_t xlo = (uint_t)xi64;
        uint_t xhi = (uint_t)(xi64 >> 32);
        float pi = (float)acc[0 + ch][rr] * Sf + bf2f(xlo & 0xffffu);
        float pf = (float)acc[2 + ch][rr] * Sf + bf2f(xlo >> 16);
        float pg = (float)acc[4 + ch][rr] * Sf + bf2f(xhi & 0xffffu);
        float po = (float)acc[6 + ch][rr] * Sf + bf2f(xhi >> 16);
        float hh = 0.f;
        if (valid) {
          float cs = sig_fast(pf) * cst[rr * 2 + ch] + sig_fast(pi) * tanh_fast(pg);
          cst[rr * 2 + ch] = cs;
          hh = sig_fast(po) * tanh_fast(cs);
          if (q >= p0)
            __builtin_nontemporal_store(f2bf(hh),
                Hb + (size_t)t * HID + w * 64 + ch * 32 + lm);
        }
        Abuf[r][w * 64 + ch * 32 + lm] = (char)(int)rintf(hh * 127.f);
      }
    }
    __syncthreads();
  }
}

// ---------------- epilogue: out = tanh((H1+H3) @ nlW^T + nlb), fp32 --------
__global__ __launch_bounds__(256, 2) void gemm_nl_kernel(
    const ushort_t* __restrict__ H1b, const ushort_t* __restrict__ H3b,
    const ushort_t* __restrict__ PBnl, const float* __restrict__ nlb,
    float* __restrict__ OutF) {
  int tid = threadIdx.x;
  int w = tid >> 6, l = tid & 63, hi = l >> 5, lm = l & 31;
  int mb = blockIdx.x, nb = blockIdx.y;
  int m = mb * 128 + w * 32 + lm;
  const s16x8* pbn = ((const s16x8*)PBnl) + (size_t)nb * 4096;
  const s16x8* a1 = (const s16x8*)(H1b + (size_t)m * 256);
  const s16x8* a3 = (const s16x8*)(H3b + (size_t)m * 256);
  f32x16 acc[4];
#pragma unroll
  for (int t = 0; t < 4; ++t)
#pragma unroll
    for (int e = 0; e < 16; ++e) acc[t][e] = 0.f;
#pragma unroll
  for (int s16 = 0; s16 < 16; ++s16) {
    s16x8 af1 = a1[s16 * 2 + hi];
    s16x8 af3 = a3[s16 * 2 + hi];
#pragma unroll
    for (int t = 0; t < 4; ++t) {
      s16x8 bf = pbn[(size_t)(s16 * 4 + t) * 64 + l];
      acc[t] = __builtin_amdgcn_mfma_f32_32x32x16_bf16(af1, bf, acc[t], 0, 0, 0);
      acc[t] = __builtin_amdgcn_mfma_f32_32x32x16_bf16(af3, bf, acc[t], 0, 0, 0);
    }
  }
  float bb[4];
#pragma unroll
  for (int t = 0; t < 4; ++t) bb[t] = nlb[nb * 128 + t * 32 + lm];
#pragma unroll
  for (int rr = 0; rr < 16; ++rr) {
    int r  = (rr & 3) + ((rr >> 2) << 3) + (hi << 2);
    int mo = mb * 128 + w * 32 + r;
    if (mo >= N_OUT) continue;
#pragma unroll
    for (int t = 0; t < 4; ++t)
      OutF[(size_t)mo * 256 + nb * 128 + t * 32 + lm] = tanh_fast(acc[t][rr] + bb[t]);
  }
}

// ---------------- final 4-way head ----------------
__global__ void pred_kernel(const float* __restrict__ outb,
                            const float* __restrict__ scW,
                            const float* __restrict__ scb,
                            float* __restrict__ pred) {
  int idx = blockIdx.x * blockDim.x + threadIdx.x;
  if (idx >= N_OUT * NDEC) return;
  int t = idx >> 2, e = idx & 3;
  const float* orow = outb + (size_t)t * HID;
  const float* wrow = scW + e * HID;
  float s = 0.f;
#pragma unroll 4
  for (int k = 0; k < HID; k += 4) {
    float4 ov = *(const float4*)(orow + k);
    float4 wv = *(const float4*)(wrow + k);
    s = fmaf(ov.x, wv.x, s);
    s = fmaf(ov.y, wv.y, s);
    s = fmaf(ov.z, wv.z, s);
    s = fmaf(ov.w, wv.w, s);
  }
  pred[idx] = s + scb[e];
}

extern "C" void kernel_launch(void* const* d_in, const int* in_sizes, int n_in,
                              void* d_out, int out_size, void* d_ws, size_t ws_size,
                              hipStream_t stream) {
  if (ws_size < WS_FLOATS * sizeof(float)) return;

  const float* train = (const float*)d_in[0];
  const int*   idxs  = (const int*)d_in[1];
  const float* a0    = (const float*)d_in[2];
  const float* tau_p = (const float*)d_in[3];
  const float* Wih[4] = {(const float*)d_in[4], (const float*)d_in[8],
                         (const float*)d_in[12], (const float*)d_in[16]};
  const float* Whh[4] = {(const float*)d_in[5], (const float*)d_in[9],
                         (const float*)d_in[13], (const float*)d_in[17]};
  const float* bih[4] = {(const float*)d_in[6], (const float*)d_in[10],
                         (const float*)d_in[14], (const float*)d_in[18]};
  const float* bhh[4] = {(const float*)d_in[7], (const float*)d_in[11],
                         (const float*)d_in[15], (const float*)d_in[19]};
  const float* nlW = (const float*)d_in[20];
  const float* nlb = (const float*)d_in[21];
  const float* scW = (const float*)d_in[22];
  const float* scb = (const float*)d_in[23];

  float* ws   = (float*)d_ws;
  float* levs = ws + LEVS_OFF;
  char* PBW8[4]; ushort_t* PBI[4]; float* Bsum[4]; ushort_t* Hb[4];
  for (int lidx = 0; lidx < 4; ++lidx) {
    PBW8[lidx] = (char*)(ws + PBW8_OFF(lidx));
    Bsum[lidx] = ws + BS_OFF(lidx);
    Hb[lidx]   = (ushort_t*)(ws + HB_OFF(lidx));
  }
  uint_t* SC = (uint_t*)(ws + SC_OFF);
  PBI[0] = (ushort_t*)(ws + PBI0_OFF);
  for (int lidx = 1; lidx < 4; ++lidx) PBI[lidx] = (ushort_t*)(ws + PBI_OFF(lidx));
  ushort_t* PBnl = (ushort_t*)(ws + PBNL_OFF);
  ushort_t* XPb  = (ushort_t*)(ws + XPB_OFF);
  float* OutF = ws + OUTF_OFF;

  // ---- scales + packing ----
  hipLaunchKernelGGL(zero_sc_kernel, dim3(1), dim3(64), 0, stream, SC);
  for (int lidx = 0; lidx < 4; ++lidx)
    hipLaunchKernelGGL(wmax_kernel, dim3(64), dim3(256), 0, stream, Whh[lidx], SC + lidx);
  for (int lidx = 0; lidx < 4; ++lidx)
    hipLaunchKernelGGL(pack_pbw8_kernel, dim3(1024), dim3(256), 0, stream,
                       Whh[lidx], PBW8[lidx], SC + lidx);
  hipLaunchKernelGGL(pack_pb_kernel, dim3(512), dim3(256), 0, stream, Wih[0], PBI[0], 8);
  for (int lidx = 1; lidx < 4; ++lidx)
    hipLaunchKernelGGL(pack_pb_kernel, dim3(1024), dim3(256), 0, stream, Wih[lidx], PBI[lidx], 16);
  for (int lidx = 0; lidx < 4; ++lidx)
    hipLaunchKernelGGL(pack_b_kernel, dim3(4), dim3(256), 0, stream, bih[lidx], bhh[lidx], Bsum[lidx]);
  hipLaunchKernelGGL(pack_nl_kernel, dim3(256), dim3(256), 0, stream, nlW, PBnl);

  // ---- levels + act ----
  hipLaunchKernelGGL(levels_kernel, dim3(128), dim3(256), 0, stream, train, idxs, a0, tau_p, levs);
  hipLaunchKernelGGL(act_kernel, dim3(510), dim3(256), 0, stream, train, levs,
                     (float*)d_out + (size_t)N_OUT * NDEC);

  // ---- layer 0: d=1, Sper=8149 ----
  hipLaunchKernelGGL(gemm_win_kernel, dim3(255, 4), dim3(256), 0, stream,
                     train, levs, PBI[0], Bsum[0], XPb);
  hipLaunchKernelGGL(lstm_mfma_kernel, dim3(255), dim3(256), 0, stream,
                     XPb, PBW8[0], SC + 0, Hb[0], 1, 8149, 32593);
  // ---- layer 1: d=3, Sper=2717 ----
  hipLaunchKernelGGL(gemm_xp_kernel, dim3(255, 4), dim3(256), 0, stream,
                     Hb[0], PBI[1], Bsum[1], XPb);
  hipLaunchKernelGGL(lstm_mfma_kernel, dim3(255), dim3(256), 0, stream,
                     XPb, PBW8[1], SC + 1, Hb[1], 3, 2717, 10865);
  // ---- layer 2: d=6, Sper=1359 ----
  hipLaunchKernelGGL(gemm_xp_kernel, dim3(255, 4), dim3(256), 0, stream,
                     Hb[1], PBI[2], Bsum[2], XPb);
  hipLaunchKernelGGL(lstm_mfma_kernel, dim3(255), dim3(256), 0, stream,
                     XPb, PBW8[2], SC + 2, Hb[2], 6, 1359, 5433);
  // ---- layer 3: d=12, Sper=680 ----
  hipLaunchKernelGGL(gemm_xp_kernel, dim3(255, 4), dim3(256), 0, stream,
                     Hb[2], PBI[3], Bsum[3], XPb);
  hipLaunchKernelGGL(lstm_mfma_kernel, dim3(255), dim3(256), 0, stream,
                     XPb, PBW8[3], SC + 3, Hb[3], 12, 680, 2717);

  // ---- epilogue ----
  hipLaunchKernelGGL(gemm_nl_kernel, dim3(255, 2), dim3(256), 0, stream,
                     Hb[1], Hb[3], PBnl, nlb, OutF);
  hipLaunchKernelGGL(pred_kernel, dim3(510), dim3(256), 0, stream,
                     OutF, scW, scb, (float*)d_out);
}

// Round 9
// 1589.277 us; speedup vs baseline: 9.6722x; 3.8972x over previous
//
#include <hip/hip_runtime.h>
#include <cstddef>
#include <cstdint>

#define T_TOTAL 32768
#define IN_SZ   128
#define HID     256
#define G4      1024
#define TA      48
#define TD      12
#define NDEC    4
#define N_WINS  (T_TOTAL - IN_SZ + 1)   // 32641
#define N_OUT   (N_WINS - TA)           // 32593
#define MPAD    32640                   // padded row count (255*128)
#define WW      32
#define PP      8
#define NSTEPS  (WW + PP)               // 40
#define MCH     16                      // chains per WG

// ---------------- workspace layout (float offsets) ----------------
#define LEVS_OFF   ((size_t)0)                                    // 32768
#define PBW8_OFF(l) ((size_t)32768 + (size_t)(l)*65536)           // Whh int8 frags, 4 x 256KB
#define SC_OFF     ((size_t)294912)                               // 16 scale slots
#define PBI0_OFF   ((size_t)294928)                               // Wih0 bf16 frags, 65536
#define PBI_OFF(l) ((size_t)360464 + (size_t)((l)-1)*131072)      // Wih1..3 bf16 frags
#define PBNL_OFF   ((size_t)753680)                               // nlW frags, 32768
#define BS_OFF(l)  ((size_t)786448 + (size_t)(l)*1024)            // 4 x 1024
#define XPB_OFF    ((size_t)790544)                               // XP bf16 [32640][1024] = 16711680 fl
#define HB_OFF(l)  ((size_t)17502224 + (size_t)(l)*4177920)       // h bf16 [32640][256], 4 x
#define OUTF_OFF   ((size_t)34213904)                             // fp32 [32640][256] = 8355840
#define WS_FLOATS  ((size_t)(34213904 + 8355840))                 // 42569744 (~170 MB)

typedef short s16x8 __attribute__((ext_vector_type(8)));
typedef float f32x16 __attribute__((ext_vector_type(16)));
typedef int   i32x16 __attribute__((ext_vector_type(16)));
typedef unsigned short ushort_t;
typedef unsigned int uint_t;

typedef const __attribute__((address_space(1))) unsigned int* as1_u32p;
typedef __attribute__((address_space(3))) unsigned int* as3_u32p;
__device__ __forceinline__ void gload_lds16(const void* g, void* lds) {
  __builtin_amdgcn_global_load_lds((as1_u32p)g, (as3_u32p)lds, 16, 0, 0);
}

__device__ __forceinline__ float sig_fast(float x) {
  return __builtin_amdgcn_rcpf(1.f + __expf(-x));
}
__device__ __forceinline__ float tanh_fast(float x) {
  float ax = fabsf(x);
  float e  = __expf(-2.f * ax);
  float r  = (1.f - e) * __builtin_amdgcn_rcpf(1.f + e);
  return copysignf(r, x);
}
__device__ __forceinline__ ushort_t f2bf(float f) {
  uint_t u = __builtin_bit_cast(uint_t, f);
  uint_t r = (u + 0x7fffu + ((u >> 16) & 1u)) >> 16;
  return (ushort_t)r;
}
__device__ __forceinline__ float bf2f(uint_t us) {
  return __builtin_bit_cast(float, us << 16);
}

// ---------------- levels (contraction, 64-step lookback) ----------------
__global__ void levels_kernel(const float* __restrict__ train,
                              const int* __restrict__ idxs,
                              const float* __restrict__ a0,
                              const float* __restrict__ tau_p,
                              float* __restrict__ levs) {
  int t = blockIdx.x * blockDim.x + threadIdx.x;
  if (t >= T_TOTAL) return;
  int ix   = idxs[0];
  float a  = 1.f / (1.f + __expf(-a0[ix]));
  float fl = tau_p[ix] * 1.0f;
  int q0 = (t >= 64) ? (t - 64) : 0;
  float p = fmaxf(train[q0], fl);
  for (int s = q0 + 1; s <= t; ++s)
    p = fmaxf(a * train[s] + (1.f - a) * p, fl);
  levs[t] = p;
}

// ---------------- act output (exact) ----------------
__global__ void act_kernel(const float* __restrict__ train,
                           const float* __restrict__ levs,
                           float* __restrict__ outp) {
  int idx = blockIdx.x * blockDim.x + threadIdx.x;
  if (idx >= N_OUT * NDEC) return;
  int w = idx >> 2, dec = idx & 3;
  int base = w + IN_SZ + dec * TD;
  float m = train[base];
#pragma unroll
  for (int j = 1; j < TD; ++j) m = fmaxf(m, train[base + j]);
  outp[idx] = m / levs[w + IN_SZ - 1];
}

// ---------------- scale slots ----------------
__global__ void zero_sc_kernel(uint_t* __restrict__ sc) {
  if (threadIdx.x < 16) sc[threadIdx.x] = 0u;
}
__global__ void wmax_kernel(const float* __restrict__ W, uint_t* __restrict__ slot) {
  __shared__ float red[256];
  int tid = threadIdx.x;
  float m = 0.f;
  for (int i = blockIdx.x * 256 + tid; i < HID * G4; i += gridDim.x * 256)
    m = fmaxf(m, fabsf(W[i]));
  red[tid] = m;
  __syncthreads();
  for (int s = 128; s > 0; s >>= 1) {
    if (tid < s) red[tid] = fmaxf(red[tid], red[tid + s]);
    __syncthreads();
  }
  if (tid == 0) atomicMax(slot, __float_as_uint(red[0]));
}

// ---------------- packing ----------------
// bf16 B-frag stream: global packed col N = wv*256 + g*64 + cp ;
// frag = wv*(K16*8) + s16*8 + t ; [l][j]: k = s16*16+(l>>5)*8+j ;
// col-in-block = t*32+(l&31) -> g=t>>1, cp=(t&1)*32+(l&31)
__global__ void pack_pb_kernel(const float* __restrict__ Wsrc, ushort_t* __restrict__ PB, int K16) {
  int idx = blockIdx.x * blockDim.x + threadIdx.x;
  if (idx >= K16 * 16384) return;
  int j = idx & 7;
  int l = (idx >> 3) & 63;
  int frag = idx >> 9;
  int t = frag & 7;
  int s16 = (frag >> 3) % K16;
  int wv  = (frag >> 3) / K16;
  int K = K16 * 16;
  int k = s16 * 16 + ((l >> 5) << 3) + j;
  int g = t >> 1;
  int cp = ((t & 1) << 5) + (l & 31);
  int orow = g * HID + wv * 64 + cp;
  PB[idx] = f2bf(Wsrc[(size_t)orow * K + k]);
}
// int8 B-frag stream for Whh (mfma_i32_32x32x16_i8, same frag geometry)
__global__ void pack_pbw8_kernel(const float* __restrict__ Whh, char* __restrict__ PB8,
                                 const uint_t* __restrict__ slot) {
  int idx = blockIdx.x * blockDim.x + threadIdx.x;
  if (idx >= 262144) return;
  float inv = 127.f / __uint_as_float(slot[0]);
  int j = idx & 7;
  int l = (idx >> 3) & 63;
  int frag = idx >> 9;
  int t = frag & 7;
  int s16 = (frag >> 3) & 15;
  int wv  = frag >> 7;
  int k = s16 * 16 + ((l >> 5) << 3) + j;
  int g = t >> 1;
  int cp = ((t & 1) << 5) + (l & 31);
  int orow = g * HID + wv * 64 + cp;
  float q = rintf(Whh[(size_t)orow * HID + k] * inv);
  q = fmaxf(-127.f, fminf(127.f, q));
  PB8[idx] = (char)(int)q;
}
// nlW frags: natural cols, N=256 as 2 blocks of 128 (4 tiles each)
__global__ void pack_nl_kernel(const float* __restrict__ nlW, ushort_t* __restrict__ PBnl) {
  int idx = blockIdx.x * blockDim.x + threadIdx.x;
  if (idx >= 65536) return;
  int j = idx & 7;
  int l = (idx >> 3) & 63;
  int frag = idx >> 9;
  int t = frag & 3;
  int s16 = (frag >> 2) & 15;
  int nb = frag >> 6;
  int n = nb * 128 + t * 32 + (l & 31);
  int k = s16 * 16 + ((l >> 5) << 3) + j;
  PBnl[idx] = f2bf(nlW[(size_t)n * HID + k]);
}
__global__ void pack_b_kernel(const float* __restrict__ bih, const float* __restrict__ bhh,
                              float* __restrict__ bs) {
  int idx = blockIdx.x * blockDim.x + threadIdx.x;
  if (idx >= G4) return;
  int g = (idx >> 6) & 3;
  int c = ((idx >> 8) << 6) + (idx & 63);
  bs[idx] = bih[g * HID + c] + bhh[g * HID + c];
}

// ---------------- MFMA input-projection GEMM (layers 1-3) ----------------
__global__ __launch_bounds__(256, 1) void gemm_xp_kernel(
    const ushort_t* __restrict__ Ab,   // [MPAD][256] bf16 (h of prev layer)
    const ushort_t* __restrict__ PBih, // frag stream (K16=16)
    const float* __restrict__ Bsum,    // [1024] gate-major packed
    ushort_t* __restrict__ XPb) {      // [MPAD][1024]
  int tid = threadIdx.x;
  int w = tid >> 6, l = tid & 63, hi = l >> 5, lm = l & 31;
  int mb = blockIdx.x, nb = blockIdx.y;
  int m = mb * 128 + w * 32 + lm;
  const s16x8* pbw = ((const s16x8*)PBih) + (size_t)nb * 8192;
  const s16x8* arow = (const s16x8*)(Ab + (size_t)m * 256);
  f32x16 acc[8];
#pragma unroll
  for (int t = 0; t < 8; ++t)
#pragma unroll
    for (int e = 0; e < 16; ++e) acc[t][e] = 0.f;
#pragma unroll
  for (int s16 = 0; s16 < 16; ++s16) {
    s16x8 af = arow[s16 * 2 + hi];
#pragma unroll
    for (int t = 0; t < 8; ++t) {
      s16x8 bf = pbw[(size_t)(s16 * 8 + t) * 64 + l];
      acc[t] = __builtin_amdgcn_mfma_f32_32x32x16_bf16(af, bf, acc[t], 0, 0, 0);
    }
  }
  float bsv[8];
#pragma unroll
  for (int t = 0; t < 8; ++t) bsv[t] = Bsum[nb * 256 + t * 32 + lm];
#pragma unroll
  for (int rr = 0; rr < 16; ++rr) {
    int r  = (rr & 3) + ((rr >> 2) << 3) + (hi << 2);
    int mo = mb * 128 + w * 32 + r;
    if (mo >= N_OUT) continue;
#pragma unroll
    for (int ch = 0; ch < 2; ++ch) {
      uint_t lo = (uint_t)f2bf(acc[0 + ch][rr] + bsv[0 + ch]) |
                  ((uint_t)f2bf(acc[2 + ch][rr] + bsv[2 + ch]) << 16);
      uint_t hi2 = (uint_t)f2bf(acc[4 + ch][rr] + bsv[4 + ch]) |
                   ((uint_t)f2bf(acc[6 + ch][rr] + bsv[6 + ch]) << 16);
      *(uint64_t*)(XPb + (size_t)mo * 1024 + nb * 256 + (ch * 32 + lm) * 4) =
          (uint64_t)lo | ((uint64_t)hi2 << 32);
    }
  }
}

// ---------------- layer-0 window projection (A built from train/lev) -------
__global__ __launch_bounds__(256, 1) void gemm_win_kernel(
    const float* __restrict__ train, const float* __restrict__ levs,
    const ushort_t* __restrict__ PBih0, // frag stream (K16=8)
    const float* __restrict__ Bsum,
    ushort_t* __restrict__ XPb) {
  int tid = threadIdx.x;
  int w = tid >> 6, l = tid & 63, hi = l >> 5, lm = l & 31;
  int mb = blockIdx.x, nb = blockIdx.y;
  int m = mb * 128 + w * 32 + lm;                 // <= 32639; train reads <= 32766
  float s = 1.f / levs[m + IN_SZ - 1];
  const s16x8* pbw = ((const s16x8*)PBih0) + (size_t)nb * 4096;
  f32x16 acc[8];
#pragma unroll
  for (int t = 0; t < 8; ++t)
#pragma unroll
    for (int e = 0; e < 16; ++e) acc[t][e] = 0.f;
#pragma unroll
  for (int s16 = 0; s16 < 8; ++s16) {
    const float* tp = train + m + s16 * 16 + hi * 8;
    s16x8 af;
#pragma unroll
    for (int j = 0; j < 8; ++j) af[j] = (short)f2bf(tp[j] * s);
#pragma unroll
    for (int t = 0; t < 8; ++t) {
      s16x8 bf = pbw[(size_t)(s16 * 8 + t) * 64 + l];
      acc[t] = __builtin_amdgcn_mfma_f32_32x32x16_bf16(af, bf, acc[t], 0, 0, 0);
    }
  }
  float bsv[8];
#pragma unroll
  for (int t = 0; t < 8; ++t) bsv[t] = Bsum[nb * 256 + t * 32 + lm];
#pragma unroll
  for (int rr = 0; rr < 16; ++rr) {
    int r  = (rr & 3) + ((rr >> 2) << 3) + (hi << 2);
    int mo = mb * 128 + w * 32 + r;
    if (mo >= N_OUT) continue;
#pragma unroll
    for (int ch = 0; ch < 2; ++ch) {
      uint_t lo = (uint_t)f2bf(acc[0 + ch][rr] + bsv[0 + ch]) |
                  ((uint_t)f2bf(acc[2 + ch][rr] + bsv[2 + ch]) << 16);
      uint_t hi2 = (uint_t)f2bf(acc[4 + ch][rr] + bsv[4 + ch]) |
                   ((uint_t)f2bf(acc[6 + ch][rr] + bsv[6 + ch]) << 16);
      *(uint64_t*)(XPb + (size_t)mo * 1024 + nb * 256 + (ch * 32 + lm) * 4) =
          (uint64_t)lo | ((uint64_t)hi2 << 32);
    }
  }
}

// ---------------- MFMA segment-parallel LSTM (v7: M=16, P=8, W=32) --------
// 255 WGs x 4 waves, 16 chains/WG. Whh int8 fully VGPR-resident. XP rows
// double-buffered into LDS via global_load_lds (re-read amplification 5x).
__global__ __launch_bounds__(256, 1) void lstm_mfma_kernel(
    const ushort_t* __restrict__ XPb,  // [MPAD][1024] bf16 gate-packed
    const char* __restrict__ PB8,      // Whh int8 frag stream
    const uint_t* __restrict__ slot,   // absmax slot
    ushort_t* __restrict__ Hb,         // [MPAD][256] bf16
    int d, int Sper, int L) {
  __shared__ char Abuf[32][264];            // 8.4 KB (h int8; rows 16-31 stay 0)
  __shared__ ushort_t XPs[2][MCH][1024];    // 64 KB
  const int tid = threadIdx.x;
  const int w  = tid >> 6;
  const int l  = tid & 63;
  const int hi = l >> 5;
  const int lm = l & 31;

  for (int idx = tid; idx < 32 * 264; idx += 256) (&Abuf[0][0])[idx] = 0;

  const float Sf = __uint_as_float(slot[0]) * (1.f / (127.f * 127.f));

  // gate-phase chain meta: 8 (rr) x 2 (ch) chains per thread cover r<16
  int meta[8];
#pragma unroll
  for (int rr = 0; rr < 8; ++rr) {
    int r  = (rr & 3) + ((rr >> 2) << 3) + (hi << 2);   // 0..15
    int id = blockIdx.x * MCH + r;
    int dl = id / Sper;
    int s  = id - dl * Sper;
    int p0 = (dl >= d) ? L : s * PP;   // sentinel: never writes (q>=p0 false)
    int ds = (dl >= d) ? 0 : dl;
    meta[rr] = p0 | (ds << 20);
  }
  float cst[16];
#pragma unroll
  for (int z = 0; z < 16; ++z) cst[z] = 0.f;

  // staging meta for this wave's 4 rows (wave-uniform -> SGPR)
  int tb[4], tc[4];
#pragma unroll
  for (int j = 0; j < 4; ++j) {
    int r  = w * 4 + j;
    int id = blockIdx.x * MCH + r;
    int dl = id / Sper;
    int s  = id - dl * Sper;
    int p0 = (dl >= d) ? L : s * PP;
    int ds = (dl >= d) ? 0 : dl;
    int q0 = p0 - WW; if (q0 < 0) q0 = 0;
    int p1 = p0 + PP; if (p1 > L) p1 = L;
    int tmax = (p1 - 1) * d + ds;
    if (tmax > N_OUT - 1) tmax = N_OUT - 1;
    tb[j] = __builtin_amdgcn_readfirstlane(q0 * d + ds);
    tc[j] = __builtin_amdgcn_readfirstlane(tmax);
  }

  // resident int8 weights: 16 k-chunks x 8 tiles x 8B = 256 VGPRs
  long wq[16][8];
  {
    const char* pw = PB8 + ((size_t)w << 16) + (size_t)l * 8;
#pragma unroll
    for (int s16 = 0; s16 < 16; ++s16)
#pragma unroll
      for (int t = 0; t < 8; ++t)
        wq[s16][t] = *(const long*)(pw + (size_t)(s16 * 8 + t) * 512);
  }

  // prologue: stage step 0 XP rows into buf 0
#pragma unroll
  for (int j = 0; j < 4; ++j) {
    int t0 = tb[j]; if (t0 > tc[j]) t0 = tc[j];
    const char* src = (const char*)XPb + (size_t)t0 * 2048 + (size_t)l * 16;
    gload_lds16(src,        (char*)&XPs[0][w * 4 + j][0]);
    gload_lds16(src + 1024, (char*)&XPs[0][w * 4 + j][512]);
  }
  __syncthreads();   // drains vmcnt (DMA) before first use

#pragma unroll 1
  for (int i = 0; i < NSTEPS; ++i) {
    // stage step i+1 into buf (i+1)&1 (overlaps with MFMA phase)
    if (i + 1 < NSTEPS) {
      const int nbuf = (i + 1) & 1;
#pragma unroll
      for (int j = 0; j < 4; ++j) {
        int t = tb[j] + (i + 1) * d;
        if (t > tc[j]) t = tc[j];
        const char* src = (const char*)XPb + (size_t)t * 2048 + (size_t)l * 16;
        gload_lds16(src,        (char*)&XPs[nbuf][w * 4 + j][0]);
        gload_lds16(src + 1024, (char*)&XPs[nbuf][w * 4 + j][512]);
      }
    }

    // MFMA phase: preacts from resident weights + Abuf
    i32x16 acc[8];
#pragma unroll
    for (int t = 0; t < 8; ++t)
#pragma unroll
      for (int e = 0; e < 16; ++e) acc[t][e] = 0;
#pragma unroll
    for (int s16 = 0; s16 < 16; ++s16) {
      long af = *(const long*)&Abuf[lm][s16 * 16 + hi * 8];
#pragma unroll
      for (int t = 0; t < 8; ++t)
        acc[t] = __builtin_amdgcn_mfma_i32_32x32x16_i8(af, wq[s16][t], acc[t], 0, 0, 0);
    }
    __syncthreads();   // Abuf reads done; DMA for i+1 drained

    // gate phase: lane-local i,f,g,o; XP from LDS
    const int buf = i & 1;
#pragma unroll
    for (int rr = 0; rr < 8; ++rr) {
      int mv = meta[rr];
      int p0 = mv & 0xFFFFF;
      int dl = mv >> 20;
      int q0 = p0 - WW; if (q0 < 0) q0 = 0;
      int q  = q0 + i;
      int p1 = p0 + PP; if (p1 > L) p1 = L;
      int t  = q * d + dl;
      bool valid = (q < p1) && (t < N_OUT);
      int r  = (rr & 3) + ((rr >> 2) << 3) + (hi << 2);
#pragma unroll
      for (int ch = 0; ch < 2; ++ch) {
        uint64_t xi64 = *(const uint64_t*)&XPs[buf][r][w * 256 + (ch * 32 + lm) * 4];
        uint_t xlo = (uint_t)xi64;
        uint_t xhi = (uint_t)(xi64 >> 32);
        float pi = (float)acc[0 + ch][rr] * Sf + bf2f(xlo & 0xffffu);
        float pf = (float)acc[2 + ch][rr] * Sf + bf2f(xlo >> 16);
        float pg = (float)acc[4 + ch][rr] * Sf + bf2f(xhi & 0xffffu);
        float po = (float)acc[6 + ch][rr] * Sf + bf2f(xhi >> 16);
        float hh = 0.f;
        if (valid) {
          float cs = sig_fast(pf) * cst[rr * 2 + ch] + sig_fast(pi) * tanh_fast(pg);
          cst[rr * 2 + ch] = cs;
          hh = sig_fast(po) * tanh_fast(cs);
          if (q >= p0)
            Hb[(size_t)t * HID + w * 64 + ch * 32 + lm] = f2bf(hh);
        }
        Abuf[r][w * 64 + ch * 32 + lm] = (char)(int)rintf(hh * 127.f);
      }
    }
    __syncthreads();
  }
}

// ---------------- epilogue: out = tanh((H1+H3) @ nlW^T + nlb), fp32 --------
__global__ __launch_bounds__(256, 2) void gemm_nl_kernel(
    const ushort_t* __restrict__ H1b, const ushort_t* __restrict__ H3b,
    const ushort_t* __restrict__ PBnl, const float* __restrict__ nlb,
    float* __restrict__ OutF) {
  int tid = threadIdx.x;
  int w = tid >> 6, l = tid & 63, hi = l >> 5, lm = l & 31;
  int mb = blockIdx.x, nb = blockIdx.y;
  int m = mb * 128 + w * 32 + lm;
  const s16x8* pbn = ((const s16x8*)PBnl) + (size_t)nb * 4096;
  const s16x8* a1 = (const s16x8*)(H1b + (size_t)m * 256);
  const s16x8* a3 = (const s16x8*)(H3b + (size_t)m * 256);
  f32x16 acc[4];
#pragma unroll
  for (int t = 0; t < 4; ++t)
#pragma unroll
    for (int e = 0; e < 16; ++e) acc[t][e] = 0.f;
#pragma unroll
  for (int s16 = 0; s16 < 16; ++s16) {
    s16x8 af1 = a1[s16 * 2 + hi];
    s16x8 af3 = a3[s16 * 2 + hi];
#pragma unroll
    for (int t = 0; t < 4; ++t) {
      s16x8 bf = pbn[(size_t)(s16 * 4 + t) * 64 + l];
      acc[t] = __builtin_amdgcn_mfma_f32_32x32x16_bf16(af1, bf, acc[t], 0, 0, 0);
      acc[t] = __builtin_amdgcn_mfma_f32_32x32x16_bf16(af3, bf, acc[t], 0, 0, 0);
    }
  }
  float bb[4];
#pragma unroll
  for (int t = 0; t < 4; ++t) bb[t] = nlb[nb * 128 + t * 32 + lm];
#pragma unroll
  for (int rr = 0; rr < 16; ++rr) {
    int r  = (rr & 3) + ((rr >> 2) << 3) + (hi << 2);
    int mo = mb * 128 + w * 32 + r;
    if (mo >= N_OUT) continue;
#pragma unroll
    for (int t = 0; t < 4; ++t)
      OutF[(size_t)mo * 256 + nb * 128 + t * 32 + lm] = tanh_fast(acc[t][rr] + bb[t]);
  }
}

// ---------------- final 4-way head ----------------
__global__ void pred_kernel(const float* __restrict__ outb,
                            const float* __restrict__ scW,
                            const float* __restrict__ scb,
                            float* __restrict__ pred) {
  int idx = blockIdx.x * blockDim.x + threadIdx.x;
  if (idx >= N_OUT * NDEC) return;
  int t = idx >> 2, e = idx & 3;
  const float* orow = outb + (size_t)t * HID;
  const float* wrow = scW + e * HID;
  float s = 0.f;
#pragma unroll 4
  for (int k = 0; k < HID; k += 4) {
    float4 ov = *(const float4*)(orow + k);
    float4 wv = *(const float4*)(wrow + k);
    s = fmaf(ov.x, wv.x, s);
    s = fmaf(ov.y, wv.y, s);
    s = fmaf(ov.z, wv.z, s);
    s = fmaf(ov.w, wv.w, s);
  }
  pred[idx] = s + scb[e];
}

extern "C" void kernel_launch(void* const* d_in, const int* in_sizes, int n_in,
                              void* d_out, int out_size, void* d_ws, size_t ws_size,
                              hipStream_t stream) {
  if (ws_size < WS_FLOATS * sizeof(float)) return;

  const float* train = (const float*)d_in[0];
  const int*   idxs  = (const int*)d_in[1];
  const float* a0    = (const float*)d_in[2];
  const float* tau_p = (const float*)d_in[3];
  const float* Wih[4] = {(const float*)d_in[4], (const float*)d_in[8],
                         (const float*)d_in[12], (const float*)d_in[16]};
  const float* Whh[4] = {(const float*)d_in[5], (const float*)d_in[9],
                         (const float*)d_in[13], (const float*)d_in[17]};
  const float* bih[4] = {(const float*)d_in[6], (const float*)d_in[10],
                         (const float*)d_in[14], (const float*)d_in[18]};
  const float* bhh[4] = {(const float*)d_in[7], (const float*)d_in[11],
                         (const float*)d_in[15], (const float*)d_in[19]};
  const float* nlW = (const float*)d_in[20];
  const float* nlb = (const float*)d_in[21];
  const float* scW = (const float*)d_in[22];
  const float* scb = (const float*)d_in[23];

  float* ws   = (float*)d_ws;
  float* levs = ws + LEVS_OFF;
  char* PBW8[4]; ushort_t* PBI[4]; float* Bsum[4]; ushort_t* Hb[4];
  for (int lidx = 0; lidx < 4; ++lidx) {
    PBW8[lidx] = (char*)(ws + PBW8_OFF(lidx));
    Bsum[lidx] = ws + BS_OFF(lidx);
    Hb[lidx]   = (ushort_t*)(ws + HB_OFF(lidx));
  }
  uint_t* SC = (uint_t*)(ws + SC_OFF);
  PBI[0] = (ushort_t*)(ws + PBI0_OFF);
  for (int lidx = 1; lidx < 4; ++lidx) PBI[lidx] = (ushort_t*)(ws + PBI_OFF(lidx));
  ushort_t* PBnl = (ushort_t*)(ws + PBNL_OFF);
  ushort_t* XPb  = (ushort_t*)(ws + XPB_OFF);
  float* OutF = ws + OUTF_OFF;

  // ---- scales + packing ----
  hipLaunchKernelGGL(zero_sc_kernel, dim3(1), dim3(64), 0, stream, SC);
  for (int lidx = 0; lidx < 4; ++lidx)
    hipLaunchKernelGGL(wmax_kernel, dim3(64), dim3(256), 0, stream, Whh[lidx], SC + lidx);
  for (int lidx = 0; lidx < 4; ++lidx)
    hipLaunchKernelGGL(pack_pbw8_kernel, dim3(1024), dim3(256), 0, stream,
                       Whh[lidx], PBW8[lidx], SC + lidx);
  hipLaunchKernelGGL(pack_pb_kernel, dim3(512), dim3(256), 0, stream, Wih[0], PBI[0], 8);
  for (int lidx = 1; lidx < 4; ++lidx)
    hipLaunchKernelGGL(pack_pb_kernel, dim3(1024), dim3(256), 0, stream, Wih[lidx], PBI[lidx], 16);
  for (int lidx = 0; lidx < 4; ++lidx)
    hipLaunchKernelGGL(pack_b_kernel, dim3(4), dim3(256), 0, stream, bih[lidx], bhh[lidx], Bsum[lidx]);
  hipLaunchKernelGGL(pack_nl_kernel, dim3(256), dim3(256), 0, stream, nlW, PBnl);

  // ---- levels + act ----
  hipLaunchKernelGGL(levels_kernel, dim3(128), dim3(256), 0, stream, train, idxs, a0, tau_p, levs);
  hipLaunchKernelGGL(act_kernel, dim3(510), dim3(256), 0, stream, train, levs,
                     (float*)d_out + (size_t)N_OUT * NDEC);

  // ---- layer 0: d=1, Sper=4075 ----
  hipLaunchKernelGGL(gemm_win_kernel, dim3(255, 4), dim3(256), 0, stream,
                     train, levs, PBI[0], Bsum[0], XPb);
  hipLaunchKernelGGL(lstm_mfma_kernel, dim3(255), dim3(256), 0, stream,
                     XPb, PBW8[0], SC + 0, Hb[0], 1, 4075, 32593);
  // ---- layer 1: d=3, Sper=1359 ----
  hipLaunchKernelGGL(gemm_xp_kernel, dim3(255, 4), dim3(256), 0, stream,
                     Hb[0], PBI[1], Bsum[1], XPb);
  hipLaunchKernelGGL(lstm_mfma_kernel, dim3(255), dim3(256), 0, stream,
                     XPb, PBW8[1], SC + 1, Hb[1], 3, 1359, 10865);
  // ---- layer 2: d=6, Sper=680 ----
  hipLaunchKernelGGL(gemm_xp_kernel, dim3(255, 4), dim3(256), 0, stream,
                     Hb[1], PBI[2], Bsum[2], XPb);
  hipLaunchKernelGGL(lstm_mfma_kernel, dim3(255), dim3(256), 0, stream,
                     XPb, PBW8[2], SC + 2, Hb[2], 6, 680, 5433);
  // ---- layer 3: d=12, Sper=340 ----
  hipLaunchKernelGGL(gemm_xp_kernel, dim3(255, 4), dim3(256), 0, stream,
                     Hb[2], PBI[3], Bsum[3], XPb);
  hipLaunchKernelGGL(lstm_mfma_kernel, dim3(255), dim3(256), 0, stream,
                     XPb, PBW8[3], SC + 3, Hb[3], 12, 340, 2717);

  // ---- epilogue ----
  hipLaunchKernelGGL(gemm_nl_kernel, dim3(255, 2), dim3(256), 0, stream,
                     Hb[1], Hb[3], PBnl, nlb, OutF);
  hipLaunchKernelGGL(pred_kernel, dim3(510), dim3(256), 0, stream,
                     OutF, scW, scb, (float*)d_out);
}